// Round 4
// baseline (245.329 us; speedup 1.0000x reference)
//
#include <hip/hip_runtime.h>
#include <hip/hip_bf16.h>

// MultiHeadAttention: B=4 H=12 S=2048 D=64 E=768, causal. fp32 in/out, bf16 MFMA compute.
// R3: attn gets 2-way KV-split blocks (4 waves: 2 qgrp x 2 split) + LDS merge,
//     defer-max (THR=8, log2 domain), 4-way partial reductions.

typedef __attribute__((ext_vector_type(8))) short bf16x8;
typedef __attribute__((ext_vector_type(4))) float f32x4;
typedef __attribute__((ext_vector_type(16))) float f32x16;
typedef __attribute__((ext_vector_type(4))) uint u32x4;

// ws offsets in bf16 elements
#define OFF_XB   0            // 8192*768            = 6291456
#define OFF_WT   6291456      // 3 * 12*64*768       = 1769472
#define OFF_WPT  8060928      // 768*768             =  589824
#define OFF_QKV  8650752      // 3 * 4*12*2048*64    = 18874368
#define OFF_AO   27525120     // 8192*768            = 6291456

#define SCALE_LOG2E 0.1803368801111204f   // (1/8) * log2(e)

__device__ inline ushort f2bf(float f) {
  __hip_bfloat16 h = __float2bfloat16(f);
  return *reinterpret_cast<ushort*>(&h);
}
__device__ inline uint cvt_pk(float lo, float hi) {
  uint r;
  asm("v_cvt_pk_bf16_f32 %0, %1, %2" : "=v"(r) : "v"(lo), "v"(hi));
  return r;
}

// ---------- fp32 -> bf16 bulk convert (8 elems/thread)
__global__ __launch_bounds__(256) void cvt_bf16(const float* __restrict__ src,
                                                ushort* __restrict__ dst, int n8) {
  int i = blockIdx.x * 256 + threadIdx.x;
  if (i >= n8) return;
  float4 a = *(const float4*)&src[(size_t)i * 8];
  float4 b = *(const float4*)&src[(size_t)i * 8 + 4];
  ushort u[8] = {f2bf(a.x), f2bf(a.y), f2bf(a.z), f2bf(a.w),
                 f2bf(b.x), f2bf(b.y), f2bf(b.z), f2bf(b.w)};
  *(bf16x8*)&dst[(size_t)i * 8] = *(bf16x8*)u;
}

// ---------- tiled 64x64 transpose+convert: fp32 [mat][Edim][Ddim] -> bf16 [mat][Ddim][Edim]
__global__ __launch_bounds__(256) void transpose_w(const float* __restrict__ src,
                                                   ushort* __restrict__ dst,
                                                   int Edim, int Ddim) {
  __shared__ ushort tile[64][130];
  int mat = blockIdx.y;
  int ntd = Ddim >> 6;
  int te = blockIdx.x / ntd, td = blockIdx.x % ntd;
  size_t base = (size_t)mat * Edim * Ddim;
  int t = threadIdx.x;
#pragma unroll
  for (int i = 0; i < 16; i++) {
    int idx = i * 256 + t;
    int r = idx >> 6, c = idx & 63;
    tile[r][c] = f2bf(src[base + (size_t)(te * 64 + r) * Ddim + td * 64 + c]);
  }
  __syncthreads();
#pragma unroll
  for (int i = 0; i < 16; i++) {
    int idx = i * 256 + t;
    int c = idx >> 6, r = idx & 63;
    dst[base + (size_t)(td * 64 + c) * Edim + te * 64 + r] = tile[r][c];
  }
}

// ---------- QKV projection GEMM: X[8192,768] @ Wt -> qkv bf16. grid (64, 36)
__global__ __launch_bounds__(256) void gemm_qkv(const ushort* __restrict__ X,
                                                const ushort* __restrict__ Wt,
                                                ushort* __restrict__ qkv) {
  __shared__ ushort Alds[128 * 40];
  __shared__ ushort Blds[64 * 40];
  int mb = blockIdx.x, nb = blockIdx.y;
  int t = threadIdx.x, w = t >> 6, lane = t & 63, lo = lane & 15, g = lane >> 4;
  const ushort* Wb = Wt + (size_t)nb * 49152;
  f32x4 acc[2][4];
#pragma unroll
  for (int qi = 0; qi < 2; qi++)
#pragma unroll
    for (int n = 0; n < 4; n++) acc[qi][n] = (f32x4){0.f, 0.f, 0.f, 0.f};
  int r = t >> 2, c4 = t & 3;
  for (int e0 = 0; e0 < 768; e0 += 32) {
#pragma unroll
    for (int i = 0; i < 2; i++)
      *(bf16x8*)&Alds[(i * 64 + r) * 40 + c4 * 8] =
          *(const bf16x8*)&X[(size_t)(mb * 128 + i * 64 + r) * 768 + e0 + c4 * 8];
    *(bf16x8*)&Blds[r * 40 + c4 * 8] =
        *(const bf16x8*)&Wb[(size_t)r * 768 + e0 + c4 * 8];
    __syncthreads();
    bf16x8 a0 = *(const bf16x8*)&Alds[(w * 32 + lo) * 40 + g * 8];
    bf16x8 a1 = *(const bf16x8*)&Alds[(w * 32 + 16 + lo) * 40 + g * 8];
#pragma unroll
    for (int n = 0; n < 4; n++) {
      bf16x8 b = *(const bf16x8*)&Blds[(n * 16 + lo) * 40 + g * 8];
      acc[0][n] = __builtin_amdgcn_mfma_f32_16x16x32_bf16(a0, b, acc[0][n], 0, 0, 0);
      acc[1][n] = __builtin_amdgcn_mfma_f32_16x16x32_bf16(a1, b, acc[1][n], 0, 0, 0);
    }
    __syncthreads();
  }
  int ty = nb / 12, h = nb % 12;
#pragma unroll
  for (int qi = 0; qi < 2; qi++)
#pragma unroll
    for (int n = 0; n < 4; n++) {
      int d = n * 16 + lo;
#pragma unroll
      for (int rr = 0; rr < 4; rr++) {
        int m = mb * 128 + w * 32 + qi * 16 + g * 4 + rr;
        int b = m >> 11, s = m & 2047;
        qkv[(size_t)ty * 6291456 + (size_t)(b * 12 + h) * 131072 + (size_t)s * 64 + d] =
            f2bf(acc[qi][n][rr]);
      }
    }
}

// ---------- causal flash attention, 32x32 MFMA, in-register P, 2-way KV split.
// grid: x = 32 (paired q-tiles of 64), y = 48. 256 threads = 4 waves.
// wave w: qgrp = w&1 (q rows qgrp*32..+31), split = w>>1 (kv tiles split, split+2, ...).
__global__ __launch_bounds__(256) void attn_fwd(const ushort* __restrict__ Qg,
                                                const ushort* __restrict__ Kg,
                                                const ushort* __restrict__ Vg,
                                                ushort* __restrict__ ao) {
  __shared__ __align__(16) char smem[36864];
  // Ksh[split]: [64 kv][72] ushort (9216 B each); Vsh[split]: [64 d][36] uint (9216 B each)
  // mrg (reused after loop): [2 qgrp][64 lane][36] float = 18432 B
  int x = blockIdx.x, bh = blockIdx.y;
  int qb = (x & 1) ? (x >> 1) : (31 - (x >> 1));  // pair heavy/light tiles
  int t = threadIdx.x, w = t >> 6, lane = t & 63, q31 = lane & 31, hi = lane >> 5;
  int qgrp = w & 1, split = w >> 1;
  const ushort* Q = Qg + (size_t)bh * 131072;
  const ushort* K = Kg + (size_t)bh * 131072;
  const ushort* V = Vg + (size_t)bh * 131072;
  int q0 = qb * 64;
  int qg = q0 + qgrp * 32 + q31;
  bf16x8 qf[4];
#pragma unroll
  for (int s = 0; s < 4; s++)
    qf[s] = *(const bf16x8*)&Q[(size_t)qg * 64 + s * 16 + hi * 8];
  f32x16 oacc[2];
#pragma unroll
  for (int dt = 0; dt < 2; dt++)
#pragma unroll
    for (int r = 0; r < 16; r++) oacc[dt][r] = 0.f;
  float zrun = -1e30f, lrun = 0.f;
  int nkb = qb + 1;
  int iters = (nkb + 1) >> 1;
  ushort* Kbuf = (ushort*)smem + split * 4608;
  uint* Vbuf = (uint*)(smem + 18432) + split * 2304;
  int t128 = t & 127;
  int vpr = t128 & 31, vdcb = t128 >> 5;
  for (int it = 0; it < iters; it++) {
    int kb = 2 * it + split;
    bool active = kb < nkb;
    if (active) {
      int t0 = kb * 64;
      // stage K row-major [64][72] (2 waves of this split)
#pragma unroll
      for (int i = 0; i < 4; i++) {
        int idx = i * 128 + t128;
        int r = idx >> 3, c = idx & 7;
        *(bf16x8*)&Kbuf[r * 72 + c * 8] =
            *(const bf16x8*)&K[(size_t)(t0 + r) * 64 + c * 8];
      }
      // stage V transposed pair-packed: Vbuf[d][pr] = (V[2pr][d], V[2pr+1][d])
#pragma unroll
      for (int dd = 0; dd < 2; dd++) {
        int dc = vdcb + dd * 4;
        bf16x8 va = *(const bf16x8*)&V[(size_t)(t0 + 2 * vpr) * 64 + dc * 8];
        bf16x8 vb = *(const bf16x8*)&V[(size_t)(t0 + 2 * vpr + 1) * 64 + dc * 8];
#pragma unroll
        for (int i = 0; i < 8; i++) {
          uint val = (uint)(ushort)va[i] | ((uint)(ushort)vb[i] << 16);
          Vbuf[(dc * 8 + i) * 36 + vpr] = val;
        }
      }
    }
    __syncthreads();
    if (active) {
      int t0 = kb * 64;
      bool diag = (kb == nkb - 1);
      // QK^T (swapped): st[kvt] = K_tile * Q^T -> S^T[kv][q], col q = q31
      f32x16 st[2];
#pragma unroll
      for (int kvt = 0; kvt < 2; kvt++)
#pragma unroll
        for (int r = 0; r < 16; r++) st[kvt][r] = 0.f;
#pragma unroll
      for (int kvt = 0; kvt < 2; kvt++) {
        if (!diag || kvt <= qgrp) {
#pragma unroll
          for (int s = 0; s < 4; s++) {
            bf16x8 kf = *(const bf16x8*)&Kbuf[(kvt * 32 + q31) * 72 + s * 16 + hi * 8];
            st[kvt] = __builtin_amdgcn_mfma_f32_32x32x16_bf16(kf, qf[s], st[kvt], 0, 0, 0);
          }
        }
      }
      // scale to log2 domain + causal mask, 4-way partial max
      float zm0 = -1e30f, zm1 = -1e30f, zm2 = -1e30f, zm3 = -1e30f;
#pragma unroll
      for (int kvt = 0; kvt < 2; kvt++)
#pragma unroll
        for (int r = 0; r < 16; r++) {
          float zz = st[kvt][r] * SCALE_LOG2E;
          if (diag) {
            int kvg = t0 + kvt * 32 + (r & 3) + 8 * (r >> 2) + 4 * hi;
            zz = (kvg <= qg) ? zz : -1e30f;
          }
          st[kvt][r] = zz;
          if ((r & 3) == 0) zm0 = fmaxf(zm0, zz);
          else if ((r & 3) == 1) zm1 = fmaxf(zm1, zz);
          else if ((r & 3) == 2) zm2 = fmaxf(zm2, zz);
          else zm3 = fmaxf(zm3, zz);
        }
      float zmax = fmaxf(fmaxf(zm0, zm1), fmaxf(zm2, zm3));
      zmax = fmaxf(zmax, __shfl_xor(zmax, 32));
      // defer-max: only rescale when the running max grows by > 8 (log2)
      float sfl = 1.f;
      if (!__all(zmax <= zrun + 8.f)) {
        float znew = fmaxf(zrun, zmax);
        float sf = exp2f(zrun - znew);
        zrun = znew;
        sfl = sf;
#pragma unroll
        for (int r = 0; r < 16; r++) {
          float sfr = __shfl(sf, (r & 3) + 8 * (r >> 2) + 4 * hi);
          oacc[0][r] *= sfr;
          oacc[1][r] *= sfr;
        }
      }
      // exp2 + 4-way partial sum (in place in st)
      float ts0 = 0.f, ts1 = 0.f, ts2 = 0.f, ts3 = 0.f;
#pragma unroll
      for (int kvt = 0; kvt < 2; kvt++)
#pragma unroll
        for (int r = 0; r < 16; r++) {
          float p = exp2f(st[kvt][r] - zrun);
          st[kvt][r] = p;
          if ((r & 3) == 0) ts0 += p;
          else if ((r & 3) == 1) ts1 += p;
          else if ((r & 3) == 2) ts2 += p;
          else ts3 += p;
        }
      float ts = (ts0 + ts1) + (ts2 + ts3);
      ts += __shfl_xor(ts, 32);
      lrun = lrun * sfl + ts;
      // pack P to bf16 A-frags: 16 cvt_pk + 8 permlane32_swap
      bf16x8 paf[4];
#pragma unroll
      for (int s = 0; s < 4; s++) {
        uint a = cvt_pk(st[s >> 1][(s & 1) * 8 + 0], st[s >> 1][(s & 1) * 8 + 1]);
        uint b2 = cvt_pk(st[s >> 1][(s & 1) * 8 + 2], st[s >> 1][(s & 1) * 8 + 3]);
        uint c = cvt_pk(st[s >> 1][(s & 1) * 8 + 4], st[s >> 1][(s & 1) * 8 + 5]);
        uint d = cvt_pk(st[s >> 1][(s & 1) * 8 + 6], st[s >> 1][(s & 1) * 8 + 7]);
        asm volatile("v_permlane32_swap_b32 %0, %1" : "+v"(a), "+v"(c));
        asm volatile("v_permlane32_swap_b32 %0, %1" : "+v"(b2), "+v"(d));
        u32x4 u4 = {a, b2, c, d};
        paf[s] = __builtin_bit_cast(bf16x8, u4);
      }
      // PV
#pragma unroll
      for (int s = 0; s < 4; s++) {
#pragma unroll
        for (int dt = 0; dt < 2; dt++) {
          bf16x8 vf = *(const bf16x8*)&Vbuf[(dt * 32 + q31) * 36 + s * 8 + hi * 4];
          oacc[dt] = __builtin_amdgcn_mfma_f32_32x32x16_bf16(paf[s], vf, oacc[dt], 0, 0, 0);
        }
      }
    }
    __syncthreads();
  }
  // ---- merge the two kv-splits via LDS (split 1 publishes, split 0 combines)
  float* mrg = (float*)smem;
  if (split == 1) {
    float* m = mrg + (qgrp * 64 + lane) * 36;
#pragma unroll
    for (int dt = 0; dt < 2; dt++)
#pragma unroll
      for (int r = 0; r < 16; r++) m[dt * 16 + r] = oacc[dt][r];
    m[32] = zrun;
    m[33] = lrun;
  }
  __syncthreads();
  if (split == 0) {
    float* m = mrg + (qgrp * 64 + lane) * 36;
    float z1 = m[32], l1 = m[33];
    float zm = fmaxf(zrun, z1);
    float s0 = exp2f(zrun - zm), s1 = exp2f(z1 - zm);
    float lm = lrun * s0 + l1 * s1;
    float f0r[16], f1r[16], lir[16];
#pragma unroll
    for (int r = 0; r < 16; r++) {
      int row = (r & 3) + 8 * (r >> 2) + 4 * hi;
      f0r[r] = __shfl(s0, row);
      f1r[r] = __shfl(s1, row);
      lir[r] = 1.f / __shfl(lm, row);
    }
    int hh = bh % 12, bb = bh / 12;
#pragma unroll
    for (int dt = 0; dt < 2; dt++)
#pragma unroll
      for (int r = 0; r < 16; r++) {
        int qr = q0 + qgrp * 32 + (r & 3) + 8 * (r >> 2) + 4 * hi;
        float o = (oacc[dt][r] * f0r[r] + m[dt * 16 + r] * f1r[r]) * lir[r];
        ao[(size_t)(bb * 2048 + qr) * 768 + hh * 64 + dt * 32 + q31] = f2bf(o);
      }
  }
}

// ---------- output projection: ao[8192,768] @ Wp[768,768] + bp -> out fp32. grid (64, 12)
__global__ __launch_bounds__(256) void gemm_out(const ushort* __restrict__ A,
                                                const ushort* __restrict__ Bt,
                                                const float* __restrict__ bias,
                                                float* __restrict__ out) {
  __shared__ ushort Alds[128 * 40];
  __shared__ ushort Blds[64 * 40];
  int mb = blockIdx.x, nb = blockIdx.y;
  int t = threadIdx.x, w = t >> 6, lane = t & 63, lo = lane & 15, g = lane >> 4;
  const ushort* Bb = Bt + (size_t)nb * 49152;
  f32x4 acc[2][4];
#pragma unroll
  for (int qi = 0; qi < 2; qi++)
#pragma unroll
    for (int n = 0; n < 4; n++) acc[qi][n] = (f32x4){0.f, 0.f, 0.f, 0.f};
  int r = t >> 2, c4 = t & 3;
  for (int e0 = 0; e0 < 768; e0 += 32) {
#pragma unroll
    for (int i = 0; i < 2; i++)
      *(bf16x8*)&Alds[(i * 64 + r) * 40 + c4 * 8] =
          *(const bf16x8*)&A[(size_t)(mb * 128 + i * 64 + r) * 768 + e0 + c4 * 8];
    *(bf16x8*)&Blds[r * 40 + c4 * 8] =
        *(const bf16x8*)&Bb[(size_t)r * 768 + e0 + c4 * 8];
    __syncthreads();
    bf16x8 a0 = *(const bf16x8*)&Alds[(w * 32 + lo) * 40 + g * 8];
    bf16x8 a1 = *(const bf16x8*)&Alds[(w * 32 + 16 + lo) * 40 + g * 8];
#pragma unroll
    for (int n = 0; n < 4; n++) {
      bf16x8 b = *(const bf16x8*)&Blds[(n * 16 + lo) * 40 + g * 8];
      acc[0][n] = __builtin_amdgcn_mfma_f32_16x16x32_bf16(a0, b, acc[0][n], 0, 0, 0);
      acc[1][n] = __builtin_amdgcn_mfma_f32_16x16x32_bf16(a1, b, acc[1][n], 0, 0, 0);
    }
    __syncthreads();
  }
#pragma unroll
  for (int qi = 0; qi < 2; qi++)
#pragma unroll
    for (int n = 0; n < 4; n++) {
      int col = nb * 64 + n * 16 + lo;
      float bv = bias[col];
#pragma unroll
      for (int rr = 0; rr < 4; rr++) {
        int m = mb * 128 + w * 32 + qi * 16 + g * 4 + rr;
        out[(size_t)m * 768 + col] = acc[qi][n][rr] + bv;
      }
    }
}

extern "C" void kernel_launch(void* const* d_in, const int* in_sizes, int n_in,
                              void* d_out, int out_size, void* d_ws, size_t ws_size,
                              hipStream_t stream) {
  const float* x  = (const float*)d_in[0];
  const float* Wq = (const float*)d_in[1];
  const float* Wk = (const float*)d_in[2];
  const float* Wv = (const float*)d_in[3];
  const float* Wp = (const float*)d_in[4];
  const float* bp = (const float*)d_in[5];
  float* out = (float*)d_out;
  ushort* ws = (ushort*)d_ws;

  ushort* xb  = ws + OFF_XB;
  ushort* wt  = ws + OFF_WT;
  ushort* wpt = ws + OFF_WPT;
  ushort* qkv = ws + OFF_QKV;
  ushort* ao  = ws + OFF_AO;

  cvt_bf16<<<dim3(3072), 256, 0, stream>>>(x, xb, 786432);
  transpose_w<<<dim3(12, 12), 256, 0, stream>>>(Wq, wt + 0 * 589824, 768, 64);
  transpose_w<<<dim3(12, 12), 256, 0, stream>>>(Wk, wt + 1 * 589824, 768, 64);
  transpose_w<<<dim3(12, 12), 256, 0, stream>>>(Wv, wt + 2 * 589824, 768, 64);
  transpose_w<<<dim3(144, 1), 256, 0, stream>>>(Wp, wpt, 768, 768);

  gemm_qkv<<<dim3(64, 36), 256, 0, stream>>>(xb, wt, qkv);
  attn_fwd<<<dim3(32, 48), 256, 0, stream>>>(qkv, qkv + 6291456, qkv + 2 * 6291456, ao);
  gemm_out<<<dim3(64, 12), 256, 0, stream>>>(ao, wpt, bp, out);
}

// Round 5
// 210.473 us; speedup vs baseline: 1.1656x; 1.1656x over previous
//
#include <hip/hip_runtime.h>
#include <hip/hip_bf16.h>

// MultiHeadAttention: B=4 H=12 S=2048 D=64 E=768, causal. fp32 in/out, bf16 MFMA compute.
// R4: attn rebuilt: fold-balanced chained waves (uniform 33-34 tiles), QBLK=32/wave,
//     V pre-packed transposed in gemm_qkv epilogue, T14 async staging, raw-domain max,
//     XCD-aware head grouping. Zero-conflict LDS layouts.

typedef __attribute__((ext_vector_type(8))) short bf16x8;
typedef __attribute__((ext_vector_type(4))) float f32x4;
typedef __attribute__((ext_vector_type(16))) float f32x16;
typedef __attribute__((ext_vector_type(4))) uint u32x4;

// ws offsets in bf16 elements
#define OFF_XB   0            // 8192*768            = 6291456
#define OFF_WT   6291456      // 3 * 12*64*768       = 1769472
#define OFF_WPT  8060928      // 768*768             =  589824
#define OFF_QKV  8650752      // q,k: 2 * 6291456; then vt (uints) in old v slot
#define OFF_AO   27525120     // 8192*768            = 6291456

#define SCALE_LOG2E 0.1803368801111204f   // (1/8) * log2(e)

__device__ inline ushort f2bf(float f) {
  __hip_bfloat16 h = __float2bfloat16(f);
  return *reinterpret_cast<ushort*>(&h);
}
__device__ inline uint cvt_pk(float lo, float hi) {
  uint r;
  asm("v_cvt_pk_bf16_f32 %0, %1, %2" : "=v"(r) : "v"(lo), "v"(hi));
  return r;
}

// ---------- fp32 -> bf16 bulk convert (8 elems/thread)
__global__ __launch_bounds__(256) void cvt_bf16(const float* __restrict__ src,
                                                ushort* __restrict__ dst, int n8) {
  int i = blockIdx.x * 256 + threadIdx.x;
  if (i >= n8) return;
  float4 a = *(const float4*)&src[(size_t)i * 8];
  float4 b = *(const float4*)&src[(size_t)i * 8 + 4];
  ushort u[8] = {f2bf(a.x), f2bf(a.y), f2bf(a.z), f2bf(a.w),
                 f2bf(b.x), f2bf(b.y), f2bf(b.z), f2bf(b.w)};
  *(bf16x8*)&dst[(size_t)i * 8] = *(bf16x8*)u;
}

// ---------- tiled 64x64 transpose+convert: fp32 [mat][Edim][Ddim] -> bf16 [mat][Ddim][Edim]
__global__ __launch_bounds__(256) void transpose_w(const float* __restrict__ src,
                                                   ushort* __restrict__ dst,
                                                   int Edim, int Ddim) {
  __shared__ ushort tile[64][130];
  int mat = blockIdx.y;
  int ntd = Ddim >> 6;
  int te = blockIdx.x / ntd, td = blockIdx.x % ntd;
  size_t base = (size_t)mat * Edim * Ddim;
  int t = threadIdx.x;
#pragma unroll
  for (int i = 0; i < 16; i++) {
    int idx = i * 256 + t;
    int r = idx >> 6, c = idx & 63;
    tile[r][c] = f2bf(src[base + (size_t)(te * 64 + r) * Ddim + td * 64 + c]);
  }
  __syncthreads();
#pragma unroll
  for (int i = 0; i < 16; i++) {
    int idx = i * 256 + t;
    int c = idx >> 6, r = idx & 63;
    dst[base + (size_t)(td * 64 + c) * Edim + te * 64 + r] = tile[r][c];
  }
}

// ---------- QKV projection GEMM: X[8192,768] @ Wt -> q,k normal; v packed-transposed.
// grid (64, 36): y = ty*12 + h.
__global__ __launch_bounds__(256) void gemm_qkv(const ushort* __restrict__ X,
                                                const ushort* __restrict__ Wt,
                                                ushort* __restrict__ qkv,
                                                uint* __restrict__ vtg) {
  __shared__ ushort Alds[128 * 40];
  __shared__ ushort Blds[64 * 40];
  int mb = blockIdx.x, nb = blockIdx.y;
  int t = threadIdx.x, w = t >> 6, lane = t & 63, lo = lane & 15, g = lane >> 4;
  const ushort* Wb = Wt + (size_t)nb * 49152;
  f32x4 acc[2][4];
#pragma unroll
  for (int qi = 0; qi < 2; qi++)
#pragma unroll
    for (int n = 0; n < 4; n++) acc[qi][n] = (f32x4){0.f, 0.f, 0.f, 0.f};
  int r = t >> 2, c4 = t & 3;
  for (int e0 = 0; e0 < 768; e0 += 32) {
#pragma unroll
    for (int i = 0; i < 2; i++)
      *(bf16x8*)&Alds[(i * 64 + r) * 40 + c4 * 8] =
          *(const bf16x8*)&X[(size_t)(mb * 128 + i * 64 + r) * 768 + e0 + c4 * 8];
    *(bf16x8*)&Blds[r * 40 + c4 * 8] =
        *(const bf16x8*)&Wb[(size_t)r * 768 + e0 + c4 * 8];
    __syncthreads();
    bf16x8 a0 = *(const bf16x8*)&Alds[(w * 32 + lo) * 40 + g * 8];
    bf16x8 a1 = *(const bf16x8*)&Alds[(w * 32 + 16 + lo) * 40 + g * 8];
#pragma unroll
    for (int n = 0; n < 4; n++) {
      bf16x8 b = *(const bf16x8*)&Blds[(n * 16 + lo) * 40 + g * 8];
      acc[0][n] = __builtin_amdgcn_mfma_f32_16x16x32_bf16(a0, b, acc[0][n], 0, 0, 0);
      acc[1][n] = __builtin_amdgcn_mfma_f32_16x16x32_bf16(a1, b, acc[1][n], 0, 0, 0);
    }
    __syncthreads();
  }
  int ty = nb / 12, h = nb % 12;
  if (ty < 2) {
#pragma unroll
    for (int qi = 0; qi < 2; qi++)
#pragma unroll
      for (int n = 0; n < 4; n++) {
        int d = n * 16 + lo;
#pragma unroll
        for (int rr = 0; rr < 4; rr++) {
          int m = mb * 128 + w * 32 + qi * 16 + g * 4 + rr;
          int b = m >> 11, s = m & 2047;
          qkv[(size_t)ty * 6291456 + (size_t)(b * 12 + h) * 131072 + (size_t)s * 64 + d] =
              f2bf(acc[qi][n][rr]);
        }
      }
  } else {
    // v: transposed pair-packed per head: [32 tiles][64 d][32 kv-pairs] uints
#pragma unroll
    for (int qi = 0; qi < 2; qi++)
#pragma unroll
      for (int n = 0; n < 4; n++) {
        int d = n * 16 + lo;
#pragma unroll
        for (int rr = 0; rr < 4; rr += 2) {
          int m = mb * 128 + w * 32 + qi * 16 + g * 4 + rr;
          int b = m >> 11, s = m & 2047;
          uint pk = cvt_pk(acc[qi][n][rr], acc[qi][n][rr + 1]);
          vtg[(size_t)(b * 12 + h) * 65536 + (s >> 6) * 2048 + d * 32 + ((s & 63) >> 1)] = pk;
        }
      }
  }
}

// ---------- causal flash attention, fold-balanced chained waves.
// grid: x = 768. xcd = x&7, l = x>>3: head = xcd*6 + l%6, fold-pair fp = l/6.
// 128 threads = 2 waves; wave w phase A: q-tile 2fp+w (cost fp+1 kv64-tiles),
// phase B: q-tile 2(31-fp)+w (cost 32-fp). Uniform 33 tiles per wave.
__global__ __launch_bounds__(128) void attn_fwd(const ushort* __restrict__ Qg,
                                                const ushort* __restrict__ Kg,
                                                const uint* __restrict__ Vtg,
                                                ushort* __restrict__ ao) {
  __shared__ ushort Klds[64 * 72];  // [kv][d], row stride 72
  __shared__ uint Vlds[64 * 36];    // [d][kv-pair], row stride 36
  int x = blockIdx.x;
  int xcd = x & 7, l = x >> 3;
  int head = xcd * 6 + (l % 6);
  int fp = l / 6;
  int t = threadIdx.x, w = t >> 6, q31 = t & 31, hi = (t & 63) >> 5;
  const ushort* Q = Qg + (size_t)head * 131072;
  const ushort* K = Kg + (size_t)head * 131072;
  const uint* V = Vtg + (size_t)head * 65536;
  int hh = head % 12, bb = head / 12;
  // staging index split (computed once)
  int kr = t >> 3, kc = t & 7;          // K: thread covers rows kr, kr+16, kr+32, kr+48? no:
  // idx = i*128 + t: r = idx>>3 = kr + i*16, c = kc
  for (int ph = 0; ph < 2; ph++) {
    int itile = (ph == 0) ? (2 * fp + w) : (2 * (31 - fp) + w);
    int q0 = itile * 32;
    int nkb = (ph == 0) ? (fp + 1) : (32 - fp);
    int qg = q0 + q31;
    bf16x8 qf[4];
#pragma unroll
    for (int s = 0; s < 4; s++)
      qf[s] = *(const bf16x8*)&Q[(size_t)qg * 64 + s * 16 + hi * 8];
    f32x16 oacc[2];
#pragma unroll
    for (int dt = 0; dt < 2; dt++)
#pragma unroll
      for (int r = 0; r < 16; r++) oacc[dt][r] = 0.f;
    float zrun = -1e30f, lrun = 0.f;
    // prologue: load tile 0 into regs
    bf16x8 kreg[4];
    u32x4 vreg[4];
#pragma unroll
    for (int i = 0; i < 4; i++) {
      kreg[i] = *(const bf16x8*)&K[(size_t)(i * 16 + kr) * 64 + kc * 8];
      vreg[i] = *(const u32x4*)&V[(i * 16 + kr) * 32 + kc * 4];
    }
    for (int kb = 0; kb < nkb; kb++) {
      int t0 = kb * 64;
      // write staged regs -> LDS (prev compute finished at loop-end barrier)
#pragma unroll
      for (int i = 0; i < 4; i++) {
        *(bf16x8*)&Klds[(i * 16 + kr) * 72 + kc * 8] = kreg[i];
        *(u32x4*)&Vlds[(i * 16 + kr) * 36 + kc * 4] = vreg[i];
      }
      __syncthreads();
      // T14: issue next tile's global loads now; consumed at next iteration
      if (kb + 1 < nkb) {
        int t1 = t0 + 64;
#pragma unroll
        for (int i = 0; i < 4; i++) {
          kreg[i] = *(const bf16x8*)&K[(size_t)(t1 + i * 16 + kr) * 64 + kc * 8];
          vreg[i] = *(const u32x4*)&V[(kb + 1) * 2048 + (i * 16 + kr) * 32 + kc * 4];
        }
      }
      bool diag = (kb == nkb - 1);
      bool skip1 = diag && (w == 0);  // upper 32 kv rows fully masked for even q-tiles
      // QK^T (swapped): st[kvt] = K * Q^T -> S^T[kv][q], col q = q31 (raw scores)
      f32x16 st[2];
#pragma unroll
      for (int kvt = 0; kvt < 2; kvt++)
#pragma unroll
        for (int r = 0; r < 16; r++) st[kvt][r] = 0.f;
#pragma unroll
      for (int s = 0; s < 4; s++) {
        bf16x8 kf0 = *(const bf16x8*)&Klds[q31 * 72 + s * 16 + hi * 8];
        st[0] = __builtin_amdgcn_mfma_f32_32x32x16_bf16(kf0, qf[s], st[0], 0, 0, 0);
      }
      if (!skip1) {
#pragma unroll
        for (int s = 0; s < 4; s++) {
          bf16x8 kf1 = *(const bf16x8*)&Klds[(32 + q31) * 72 + s * 16 + hi * 8];
          st[1] = __builtin_amdgcn_mfma_f32_32x32x16_bf16(kf1, qf[s], st[1], 0, 0, 0);
        }
      }
      // causal mask in raw domain (diag tile only)
      if (diag) {
#pragma unroll
        for (int kvt = 0; kvt < 2; kvt++)
#pragma unroll
          for (int r = 0; r < 16; r++) {
            int kvg = t0 + kvt * 32 + (r & 3) + 8 * (r >> 2) + 4 * hi;
            if (kvg > qg) st[kvt][r] = -3e38f;
          }
      }
      // raw max (scale after: SCALE_LOG2E > 0 preserves order)
      float zm0 = -3e38f, zm1 = -3e38f, zm2 = -3e38f, zm3 = -3e38f;
#pragma unroll
      for (int kvt = 0; kvt < 2; kvt++)
#pragma unroll
        for (int r = 0; r < 16; r++) {
          float v = st[kvt][r];
          if ((r & 3) == 0) zm0 = fmaxf(zm0, v);
          else if ((r & 3) == 1) zm1 = fmaxf(zm1, v);
          else if ((r & 3) == 2) zm2 = fmaxf(zm2, v);
          else zm3 = fmaxf(zm3, v);
        }
      float zmr = fmaxf(fmaxf(zm0, zm1), fmaxf(zm2, zm3));
      zmr = fmaxf(zmr, __shfl_xor(zmr, 32));
      float zmax = zmr * SCALE_LOG2E;
      float sfl = 1.f;
      if (!__all(zmax <= zrun + 8.f)) {
        float znew = fmaxf(zrun, zmax);
        float sf = exp2f(zrun - znew);
        zrun = znew;
        sfl = sf;
#pragma unroll
        for (int r = 0; r < 16; r++) {
          float sfr = __shfl(sf, (r & 3) + 8 * (r >> 2) + 4 * hi);
          oacc[0][r] *= sfr;
          oacc[1][r] *= sfr;
        }
      }
      // p = exp2(raw*s - zrun), 4-way partial sums, in place
      float ts0 = 0.f, ts1 = 0.f, ts2 = 0.f, ts3 = 0.f;
#pragma unroll
      for (int kvt = 0; kvt < 2; kvt++)
#pragma unroll
        for (int r = 0; r < 16; r++) {
          float p = exp2f(__builtin_fmaf(st[kvt][r], SCALE_LOG2E, -zrun));
          st[kvt][r] = p;
          if ((r & 3) == 0) ts0 += p;
          else if ((r & 3) == 1) ts1 += p;
          else if ((r & 3) == 2) ts2 += p;
          else ts3 += p;
        }
      float ts = (ts0 + ts1) + (ts2 + ts3);
      ts += __shfl_xor(ts, 32);
      lrun = lrun * sfl + ts;
      // pack P to bf16 A-frags (verified T12 layout)
      bf16x8 paf[4];
#pragma unroll
      for (int s = 0; s < 4; s++) {
        uint a = cvt_pk(st[s >> 1][(s & 1) * 8 + 0], st[s >> 1][(s & 1) * 8 + 1]);
        uint b2 = cvt_pk(st[s >> 1][(s & 1) * 8 + 2], st[s >> 1][(s & 1) * 8 + 3]);
        uint c = cvt_pk(st[s >> 1][(s & 1) * 8 + 4], st[s >> 1][(s & 1) * 8 + 5]);
        uint d = cvt_pk(st[s >> 1][(s & 1) * 8 + 6], st[s >> 1][(s & 1) * 8 + 7]);
        asm volatile("v_permlane32_swap_b32 %0, %1" : "+v"(a), "+v"(c));
        asm volatile("v_permlane32_swap_b32 %0, %1" : "+v"(b2), "+v"(d));
        u32x4 u4 = {a, b2, c, d};
        paf[s] = __builtin_bit_cast(bf16x8, u4);
      }
      // PV
#pragma unroll
      for (int s = 0; s < 4; s++) {
#pragma unroll
        for (int dt = 0; dt < 2; dt++) {
          bf16x8 vf = *(const bf16x8*)&Vlds[(dt * 32 + q31) * 36 + s * 8 + hi * 4];
          oacc[dt] = __builtin_amdgcn_mfma_f32_32x32x16_bf16(paf[s], vf, oacc[dt], 0, 0, 0);
        }
      }
      __syncthreads();
    }
    // epilogue: normalize, write
    float li[16];
#pragma unroll
    for (int r = 0; r < 16; r++)
      li[r] = 1.f / __shfl(lrun, (r & 3) + 8 * (r >> 2) + 4 * hi);
#pragma unroll
    for (int dt = 0; dt < 2; dt++)
#pragma unroll
      for (int r = 0; r < 16; r++) {
        int qr = q0 + (r & 3) + 8 * (r >> 2) + 4 * hi;
        ao[(size_t)(bb * 2048 + qr) * 768 + hh * 64 + dt * 32 + q31] =
            f2bf(oacc[dt][r] * li[r]);
      }
  }
}

// ---------- output projection: ao[8192,768] @ Wp[768,768] + bp -> out fp32. grid (64, 12)
__global__ __launch_bounds__(256) void gemm_out(const ushort* __restrict__ A,
                                                const ushort* __restrict__ Bt,
                                                const float* __restrict__ bias,
                                                float* __restrict__ out) {
  __shared__ ushort Alds[128 * 40];
  __shared__ ushort Blds[64 * 40];
  int mb = blockIdx.x, nb = blockIdx.y;
  int t = threadIdx.x, w = t >> 6, lane = t & 63, lo = lane & 15, g = lane >> 4;
  const ushort* Bb = Bt + (size_t)nb * 49152;
  f32x4 acc[2][4];
#pragma unroll
  for (int qi = 0; qi < 2; qi++)
#pragma unroll
    for (int n = 0; n < 4; n++) acc[qi][n] = (f32x4){0.f, 0.f, 0.f, 0.f};
  int r = t >> 2, c4 = t & 3;
  for (int e0 = 0; e0 < 768; e0 += 32) {
#pragma unroll
    for (int i = 0; i < 2; i++)
      *(bf16x8*)&Alds[(i * 64 + r) * 40 + c4 * 8] =
          *(const bf16x8*)&A[(size_t)(mb * 128 + i * 64 + r) * 768 + e0 + c4 * 8];
    *(bf16x8*)&Blds[r * 40 + c4 * 8] =
        *(const bf16x8*)&Bb[(size_t)r * 768 + e0 + c4 * 8];
    __syncthreads();
    bf16x8 a0 = *(const bf16x8*)&Alds[(w * 32 + lo) * 40 + g * 8];
    bf16x8 a1 = *(const bf16x8*)&Alds[(w * 32 + 16 + lo) * 40 + g * 8];
#pragma unroll
    for (int n = 0; n < 4; n++) {
      bf16x8 b = *(const bf16x8*)&Blds[(n * 16 + lo) * 40 + g * 8];
      acc[0][n] = __builtin_amdgcn_mfma_f32_16x16x32_bf16(a0, b, acc[0][n], 0, 0, 0);
      acc[1][n] = __builtin_amdgcn_mfma_f32_16x16x32_bf16(a1, b, acc[1][n], 0, 0, 0);
    }
    __syncthreads();
  }
#pragma unroll
  for (int qi = 0; qi < 2; qi++)
#pragma unroll
    for (int n = 0; n < 4; n++) {
      int col = nb * 64 + n * 16 + lo;
      float bv = bias[col];
#pragma unroll
      for (int rr = 0; rr < 4; rr++) {
        int m = mb * 128 + w * 32 + qi * 16 + g * 4 + rr;
        out[(size_t)m * 768 + col] = acc[qi][n][rr] + bv;
      }
    }
}

extern "C" void kernel_launch(void* const* d_in, const int* in_sizes, int n_in,
                              void* d_out, int out_size, void* d_ws, size_t ws_size,
                              hipStream_t stream) {
  const float* x  = (const float*)d_in[0];
  const float* Wq = (const float*)d_in[1];
  const float* Wk = (const float*)d_in[2];
  const float* Wv = (const float*)d_in[3];
  const float* Wp = (const float*)d_in[4];
  const float* bp = (const float*)d_in[5];
  float* out = (float*)d_out;
  ushort* ws = (ushort*)d_ws;

  ushort* xb  = ws + OFF_XB;
  ushort* wt  = ws + OFF_WT;
  ushort* wpt = ws + OFF_WPT;
  ushort* qkv = ws + OFF_QKV;                          // q, k
  uint*   vt  = (uint*)(ws + OFF_QKV + 2 * 6291456);   // packed-transposed v
  ushort* ao  = ws + OFF_AO;

  cvt_bf16<<<dim3(3072), 256, 0, stream>>>(x, xb, 786432);
  transpose_w<<<dim3(12, 12), 256, 0, stream>>>(Wq, wt + 0 * 589824, 768, 64);
  transpose_w<<<dim3(12, 12), 256, 0, stream>>>(Wk, wt + 1 * 589824, 768, 64);
  transpose_w<<<dim3(12, 12), 256, 0, stream>>>(Wv, wt + 2 * 589824, 768, 64);
  transpose_w<<<dim3(144, 1), 256, 0, stream>>>(Wp, wpt, 768, 768);

  gemm_qkv<<<dim3(64, 36), 256, 0, stream>>>(xb, wt, qkv, vt);
  attn_fwd<<<dim3(768), 128, 0, stream>>>(qkv, qkv + 6291456, vt, ao);
  gemm_out<<<dim3(64, 12), 256, 0, stream>>>(ao, wpt, bp, out);
}

// Round 6
// 149.494 us; speedup vs baseline: 1.6411x; 1.4079x over previous
//
#include <hip/hip_runtime.h>
#include <hip/hip_bf16.h>

// MultiHeadAttention: B=4 H=12 S=2048 D=64 E=768, causal. fp32 in/out, bf16 MFMA compute.
// R5: attn: fixed-max softmax (no max/rescale chain), l-via-MFMA(ones), 4-wave blocks
//     with shared dbuf K/V staging, LPT heavy-first dispatch, causal sub-tile skipping.
//     gemm_qkv fuses fp32->bf16 conversion of x (cvt kernel deleted).

typedef __attribute__((ext_vector_type(8))) short bf16x8;
typedef __attribute__((ext_vector_type(4))) float f32x4;
typedef __attribute__((ext_vector_type(16))) float f32x16;
typedef __attribute__((ext_vector_type(4))) uint u32x4;

// ws offsets in bf16 elements
#define OFF_WT   6291456      // 3 * 12*64*768       = 1769472
#define OFF_WPT  8060928      // 768*768             =  589824
#define OFF_QKV  8650752      // q,k: 2 * 6291456; then vt (uints) in old v slot
#define OFF_AO   27525120     // 8192*768            = 6291456

#define SCALE_LOG2E 0.1803368801111204f   // (1/8) * log2(e)

__device__ inline ushort f2bf(float f) {
  __hip_bfloat16 h = __float2bfloat16(f);
  return *reinterpret_cast<ushort*>(&h);
}
__device__ inline uint cvt_pk(float lo, float hi) {
  uint r;
  asm("v_cvt_pk_bf16_f32 %0, %1, %2" : "=v"(r) : "v"(lo), "v"(hi));
  return r;
}

// ---------- tiled 64x64 transpose+convert: fp32 [mat][Edim][Ddim] -> bf16 [mat][Ddim][Edim]
__global__ __launch_bounds__(256) void transpose_w(const float* __restrict__ src,
                                                   ushort* __restrict__ dst,
                                                   int Edim, int Ddim) {
  __shared__ ushort tile[64][130];
  int mat = blockIdx.y;
  int ntd = Ddim >> 6;
  int te = blockIdx.x / ntd, td = blockIdx.x % ntd;
  size_t base = (size_t)mat * Edim * Ddim;
  int t = threadIdx.x;
#pragma unroll
  for (int i = 0; i < 16; i++) {
    int idx = i * 256 + t;
    int r = idx >> 6, c = idx & 63;
    tile[r][c] = f2bf(src[base + (size_t)(te * 64 + r) * Ddim + td * 64 + c]);
  }
  __syncthreads();
#pragma unroll
  for (int i = 0; i < 16; i++) {
    int idx = i * 256 + t;
    int c = idx >> 6, r = idx & 63;
    dst[base + (size_t)(td * 64 + c) * Edim + te * 64 + r] = tile[r][c];
  }
}

// ---------- QKV projection GEMM: x fp32 [8192,768] @ Wt -> q,k normal; v packed-transposed.
// grid (64, 36): y = ty*12 + h.
__global__ __launch_bounds__(256) void gemm_qkv(const float* __restrict__ X,
                                                const ushort* __restrict__ Wt,
                                                ushort* __restrict__ qkv,
                                                uint* __restrict__ vtg) {
  __shared__ ushort Alds[128 * 40];
  __shared__ ushort Blds[64 * 40];
  int mb = blockIdx.x, nb = blockIdx.y;
  int t = threadIdx.x, w = t >> 6, lane = t & 63, lo = lane & 15, g = lane >> 4;
  const ushort* Wb = Wt + (size_t)nb * 49152;
  f32x4 acc[2][4];
#pragma unroll
  for (int qi = 0; qi < 2; qi++)
#pragma unroll
    for (int n = 0; n < 4; n++) acc[qi][n] = (f32x4){0.f, 0.f, 0.f, 0.f};
  int r = t >> 2, c4 = t & 3;
  for (int e0 = 0; e0 < 768; e0 += 32) {
#pragma unroll
    for (int i = 0; i < 2; i++) {
      const float* src = &X[(size_t)(mb * 128 + i * 64 + r) * 768 + e0 + c4 * 8];
      float4 f0 = *(const float4*)src;
      float4 f1 = *(const float4*)(src + 4);
      u32x4 pk = {cvt_pk(f0.x, f0.y), cvt_pk(f0.z, f0.w),
                  cvt_pk(f1.x, f1.y), cvt_pk(f1.z, f1.w)};
      *(bf16x8*)&Alds[(i * 64 + r) * 40 + c4 * 8] = __builtin_bit_cast(bf16x8, pk);
    }
    *(bf16x8*)&Blds[r * 40 + c4 * 8] =
        *(const bf16x8*)&Wb[(size_t)r * 768 + e0 + c4 * 8];
    __syncthreads();
    bf16x8 a0 = *(const bf16x8*)&Alds[(w * 32 + lo) * 40 + g * 8];
    bf16x8 a1 = *(const bf16x8*)&Alds[(w * 32 + 16 + lo) * 40 + g * 8];
#pragma unroll
    for (int n = 0; n < 4; n++) {
      bf16x8 b = *(const bf16x8*)&Blds[(n * 16 + lo) * 40 + g * 8];
      acc[0][n] = __builtin_amdgcn_mfma_f32_16x16x32_bf16(a0, b, acc[0][n], 0, 0, 0);
      acc[1][n] = __builtin_amdgcn_mfma_f32_16x16x32_bf16(a1, b, acc[1][n], 0, 0, 0);
    }
    __syncthreads();
  }
  int ty = nb / 12, h = nb % 12;
  if (ty < 2) {
#pragma unroll
    for (int qi = 0; qi < 2; qi++)
#pragma unroll
      for (int n = 0; n < 4; n++) {
        int d = n * 16 + lo;
#pragma unroll
        for (int rr = 0; rr < 4; rr++) {
          int m = mb * 128 + w * 32 + qi * 16 + g * 4 + rr;
          int b = m >> 11, s = m & 2047;
          qkv[(size_t)ty * 6291456 + (size_t)(b * 12 + h) * 131072 + (size_t)s * 64 + d] =
              f2bf(acc[qi][n][rr]);
        }
      }
  } else {
    // v: transposed pair-packed per head: [32 tiles][64 d][32 kv-pairs] uints
#pragma unroll
    for (int qi = 0; qi < 2; qi++)
#pragma unroll
      for (int n = 0; n < 4; n++) {
        int d = n * 16 + lo;
#pragma unroll
        for (int rr = 0; rr < 4; rr += 2) {
          int m = mb * 128 + w * 32 + qi * 16 + g * 4 + rr;
          int b = m >> 11, s = m & 2047;
          uint pk = cvt_pk(acc[qi][n][rr], acc[qi][n][rr + 1]);
          vtg[(size_t)(b * 12 + h) * 65536 + (s >> 6) * 2048 + d * 32 + ((s & 63) >> 1)] = pk;
        }
      }
  }
}

// ---------- causal flash attention: fixed-max softmax, l via MFMA(ones).
// grid: x = 768: head = x%48 (-> XCD x%8), qb = 15 - x/48 (heavy first).
// 256 threads = 4 waves; wave w owns q rows [qb*128 + 32w, +32). KV tiles T = 2qb+2,
// shared double-buffered staging.
__global__ __launch_bounds__(256, 3) void attn_fwd(const ushort* __restrict__ Qg,
                                                   const ushort* __restrict__ Kg,
                                                   const uint* __restrict__ Vtg,
                                                   ushort* __restrict__ ao) {
  __shared__ ushort Ksh[2][64 * 72];  // [kv][d], row stride 72 ushort
  __shared__ uint Vsh[2][64 * 36];    // [d][kv-pair], row stride 36 uint
  int x = blockIdx.x;
  int head = x % 48;
  int qb = 15 - x / 48;
  int T = 2 * qb + 2;
  int t = threadIdx.x, w = t >> 6, q31 = t & 31, hi = (t & 63) >> 5;
  const ushort* Q = Qg + (size_t)head * 131072;
  const ushort* K = Kg + (size_t)head * 131072;
  const uint* V = Vtg + (size_t)head * 65536;
  int qstart = qb * 128 + 32 * w;
  int qg = qstart + q31;
  bf16x8 qf[4];
#pragma unroll
  for (int s = 0; s < 4; s++)
    qf[s] = *(const bf16x8*)&Q[(size_t)qg * 64 + s * 16 + hi * 8];
  // ones B-fragment for l accumulation
  bf16x8 ones;
#pragma unroll
  for (int i = 0; i < 8; i++) ones[i] = (short)0x3F80;
  f32x16 oacc[2], lacc;
#pragma unroll
  for (int r = 0; r < 16; r++) { oacc[0][r] = 0.f; oacc[1][r] = 0.f; lacc[r] = 0.f; }
  // staging split: thread covers rows sr, sr+32 (16B chunks)
  int sr = t >> 3, sc = t & 7;
  bf16x8 kreg[2];
  u32x4 vreg[2];
#pragma unroll
  for (int i = 0; i < 2; i++) {
    kreg[i] = *(const bf16x8*)&K[(size_t)(i * 32 + sr) * 64 + sc * 8];
    vreg[i] = *(const u32x4*)&V[(i * 32 + sr) * 32 + sc * 4];
  }
#pragma unroll
  for (int i = 0; i < 2; i++) {
    *(bf16x8*)&Ksh[0][(i * 32 + sr) * 72 + sc * 8] = kreg[i];
    *(u32x4*)&Vsh[0][(i * 32 + sr) * 36 + sc * 4] = vreg[i];
  }
  for (int kb = 0; kb < T; kb++) {
    __syncthreads();
    // T14: issue next tile's global loads now; consumed after compute
    if (kb + 1 < T) {
      int t1 = (kb + 1) * 64;
#pragma unroll
      for (int i = 0; i < 2; i++) {
        kreg[i] = *(const bf16x8*)&K[(size_t)(t1 + i * 32 + sr) * 64 + sc * 8];
        vreg[i] = *(const u32x4*)&V[(kb + 1) * 2048 + (i * 32 + sr) * 32 + sc * 4];
      }
    }
    int t0 = kb * 64;
    if (t0 <= qstart + 31) {  // not fully masked for this wave
      const ushort* Kb = Ksh[kb & 1];
      const uint* Vb = Vsh[kb & 1];
      bool act1 = (t0 + 32 <= qstart + 31);
      // QK^T (swapped): S^T[kv][q], col q = q31
      f32x16 st0, st1;
#pragma unroll
      for (int r = 0; r < 16; r++) { st0[r] = 0.f; st1[r] = 0.f; }
#pragma unroll
      for (int s = 0; s < 4; s++) {
        bf16x8 kf = *(const bf16x8*)&Kb[q31 * 72 + s * 16 + hi * 8];
        st0 = __builtin_amdgcn_mfma_f32_32x32x16_bf16(kf, qf[s], st0, 0, 0, 0);
      }
      if (act1) {
#pragma unroll
        for (int s = 0; s < 4; s++) {
          bf16x8 kf = *(const bf16x8*)&Kb[(32 + q31) * 72 + s * 16 + hi * 8];
          st1 = __builtin_amdgcn_mfma_f32_32x32x16_bf16(kf, qf[s], st1, 0, 0, 0);
        }
      }
      // causal mask (diag sub-tiles only), elementwise in raw domain
      if (t0 + 31 > qstart) {
        int base = t0 - qstart;
#pragma unroll
        for (int r = 0; r < 16; r++) {
          int crow = (r & 3) + 8 * (r >> 2) + 4 * hi;
          if (base + crow > q31) st0[r] = -3e38f;
        }
      }
      if (act1 && (t0 + 63 > qstart)) {
        int base = t0 + 32 - qstart;
#pragma unroll
        for (int r = 0; r < 16; r++) {
          int crow = (r & 3) + 8 * (r >> 2) + 4 * hi;
          if (base + crow > q31) st1[r] = -3e38f;
        }
      }
      // fixed-max: p = exp2(s * c); masked -> 0
#pragma unroll
      for (int r = 0; r < 16; r++)
        st0[r] = __builtin_amdgcn_exp2f(st0[r] * SCALE_LOG2E);
      if (act1) {
#pragma unroll
        for (int r = 0; r < 16; r++)
          st1[r] = __builtin_amdgcn_exp2f(st1[r] * SCALE_LOG2E);
      }
      // pack P -> bf16 A-frags (T12)
      int ns = act1 ? 4 : 2;
      bf16x8 paf[4];
#pragma unroll
      for (int s = 0; s < 4; s++) {
        if (s < ns) {
          const f32x16& sv = (s < 2) ? st0 : st1;
          int rb = (s & 1) * 8;
          uint a = cvt_pk(sv[rb + 0], sv[rb + 1]);
          uint b2 = cvt_pk(sv[rb + 2], sv[rb + 3]);
          uint c = cvt_pk(sv[rb + 4], sv[rb + 5]);
          uint d = cvt_pk(sv[rb + 6], sv[rb + 7]);
          asm volatile("v_permlane32_swap_b32 %0, %1" : "+v"(a), "+v"(c));
          asm volatile("v_permlane32_swap_b32 %0, %1" : "+v"(b2), "+v"(d));
          u32x4 u4 = {a, b2, c, d};
          paf[s] = __builtin_bit_cast(bf16x8, u4);
        }
      }
      // PV + l accumulation
#pragma unroll
      for (int s = 0; s < 4; s++) {
        if (s < ns) {
          lacc = __builtin_amdgcn_mfma_f32_32x32x16_bf16(paf[s], ones, lacc, 0, 0, 0);
#pragma unroll
          for (int dt = 0; dt < 2; dt++) {
            bf16x8 vf = *(const bf16x8*)&Vb[(dt * 32 + q31) * 36 + s * 8 + hi * 4];
            oacc[dt] = __builtin_amdgcn_mfma_f32_32x32x16_bf16(paf[s], vf, oacc[dt], 0, 0, 0);
          }
        }
      }
    }
    // write staged regs -> other buffer
    if (kb + 1 < T) {
      int b2 = (kb + 1) & 1;
#pragma unroll
      for (int i = 0; i < 2; i++) {
        *(bf16x8*)&Ksh[b2][(i * 32 + sr) * 72 + sc * 8] = kreg[i];
        *(u32x4*)&Vsh[b2][(i * 32 + sr) * 36 + sc * 4] = vreg[i];
      }
    }
  }
  // epilogue: normalize by lacc (row-aligned with oacc; no cross-lane needed)
  int hh = head % 12, bb = head / 12;
#pragma unroll
  for (int dt = 0; dt < 2; dt++)
#pragma unroll
    for (int r = 0; r < 16; r++) {
      int qr = qstart + (r & 3) + 8 * (r >> 2) + 4 * hi;
      ao[(size_t)(bb * 2048 + qr) * 768 + hh * 64 + dt * 32 + q31] =
          f2bf(oacc[dt][r] / lacc[r]);
    }
}

// ---------- output projection: ao[8192,768] @ Wp[768,768] + bp -> out fp32. grid (64, 12)
__global__ __launch_bounds__(256) void gemm_out(const ushort* __restrict__ A,
                                                const ushort* __restrict__ Bt,
                                                const float* __restrict__ bias,
                                                float* __restrict__ out) {
  __shared__ ushort Alds[128 * 40];
  __shared__ ushort Blds[64 * 40];
  int mb = blockIdx.x, nb = blockIdx.y;
  int t = threadIdx.x, w = t >> 6, lane = t & 63, lo = lane & 15, g = lane >> 4;
  const ushort* Bb = Bt + (size_t)nb * 49152;
  f32x4 acc[2][4];
#pragma unroll
  for (int qi = 0; qi < 2; qi++)
#pragma unroll
    for (int n = 0; n < 4; n++) acc[qi][n] = (f32x4){0.f, 0.f, 0.f, 0.f};
  int r = t >> 2, c4 = t & 3;
  for (int e0 = 0; e0 < 768; e0 += 32) {
#pragma unroll
    for (int i = 0; i < 2; i++)
      *(bf16x8*)&Alds[(i * 64 + r) * 40 + c4 * 8] =
          *(const bf16x8*)&A[(size_t)(mb * 128 + i * 64 + r) * 768 + e0 + c4 * 8];
    *(bf16x8*)&Blds[r * 40 + c4 * 8] =
        *(const bf16x8*)&Bb[(size_t)r * 768 + e0 + c4 * 8];
    __syncthreads();
    bf16x8 a0 = *(const bf16x8*)&Alds[(w * 32 + lo) * 40 + g * 8];
    bf16x8 a1 = *(const bf16x8*)&Alds[(w * 32 + 16 + lo) * 40 + g * 8];
#pragma unroll
    for (int n = 0; n < 4; n++) {
      bf16x8 b = *(const bf16x8*)&Blds[(n * 16 + lo) * 40 + g * 8];
      acc[0][n] = __builtin_amdgcn_mfma_f32_16x16x32_bf16(a0, b, acc[0][n], 0, 0, 0);
      acc[1][n] = __builtin_amdgcn_mfma_f32_16x16x32_bf16(a1, b, acc[1][n], 0, 0, 0);
    }
    __syncthreads();
  }
#pragma unroll
  for (int qi = 0; qi < 2; qi++)
#pragma unroll
    for (int n = 0; n < 4; n++) {
      int col = nb * 64 + n * 16 + lo;
      float bv = bias[col];
#pragma unroll
      for (int rr = 0; rr < 4; rr++) {
        int m = mb * 128 + w * 32 + qi * 16 + g * 4 + rr;
        out[(size_t)m * 768 + col] = acc[qi][n][rr] + bv;
      }
    }
}

extern "C" void kernel_launch(void* const* d_in, const int* in_sizes, int n_in,
                              void* d_out, int out_size, void* d_ws, size_t ws_size,
                              hipStream_t stream) {
  const float* x  = (const float*)d_in[0];
  const float* Wq = (const float*)d_in[1];
  const float* Wk = (const float*)d_in[2];
  const float* Wv = (const float*)d_in[3];
  const float* Wp = (const float*)d_in[4];
  const float* bp = (const float*)d_in[5];
  float* out = (float*)d_out;
  ushort* ws = (ushort*)d_ws;

  ushort* wt  = ws + OFF_WT;
  ushort* wpt = ws + OFF_WPT;
  ushort* qkv = ws + OFF_QKV;                          // q, k
  uint*   vt  = (uint*)(ws + OFF_QKV + 2 * 6291456);   // packed-transposed v
  ushort* ao  = ws + OFF_AO;

  transpose_w<<<dim3(12, 12), 256, 0, stream>>>(Wq, wt + 0 * 589824, 768, 64);
  transpose_w<<<dim3(12, 12), 256, 0, stream>>>(Wk, wt + 1 * 589824, 768, 64);
  transpose_w<<<dim3(12, 12), 256, 0, stream>>>(Wv, wt + 2 * 589824, 768, 64);
  transpose_w<<<dim3(144, 1), 256, 0, stream>>>(Wp, wpt, 768, 768);

  gemm_qkv<<<dim3(64, 36), 256, 0, stream>>>(x, wt, qkv, vt);
  attn_fwd<<<dim3(768), 256, 0, stream>>>(qkv, qkv + 6291456, vt, ao);
  gemm_out<<<dim3(64, 12), 256, 0, stream>>>(ao, wpt, bp, out);
}

// Round 7
// 144.402 us; speedup vs baseline: 1.6989x; 1.0353x over previous
//
#include <hip/hip_runtime.h>
#include <hip/hip_bf16.h>

// MultiHeadAttention: B=4 H=12 S=2048 D=64 E=768, causal. fp32 in/out, bf16 MFMA compute.
// R6: both GEMMs rebuilt on the m97 recipe: global_load_lds(16B) + linear-swizzled LDS,
//     128x128 tile (qkv, 4 waves) / 128x64 (out, 2 waves), 64x64 per wave, BK=32.
//     x pre-converted to bf16. attn unchanged from R5.

typedef __attribute__((ext_vector_type(8))) short bf16x8;
typedef __attribute__((ext_vector_type(4))) float f32x4;
typedef __attribute__((ext_vector_type(16))) float f32x16;
typedef __attribute__((ext_vector_type(4))) uint u32x4;

// ws offsets in bf16 elements
#define OFF_XB   0            // 8192*768            = 6291456
#define OFF_WT   6291456      // 3 * 12*64*768       = 1769472
#define OFF_WPT  8060928      // 768*768             =  589824
#define OFF_QKV  8650752      // q,k: 2 * 6291456; then vt (uints)
#define OFF_AO   27525120     // 8192*768            = 6291456

#define SCALE_LOG2E 0.1803368801111204f   // (1/8) * log2(e)

__device__ inline ushort f2bf(float f) {
  __hip_bfloat16 h = __float2bfloat16(f);
  return *reinterpret_cast<ushort*>(&h);
}
__device__ inline uint cvt_pk(float lo, float hi) {
  uint r;
  asm("v_cvt_pk_bf16_f32 %0, %1, %2" : "=v"(r) : "v"(lo), "v"(hi));
  return r;
}
#define GLOAD16(g, l)                                                              \
  __builtin_amdgcn_global_load_lds(                                                \
      (const __attribute__((address_space(1))) uint*)(g),                          \
      (__attribute__((address_space(3))) uint*)(l), 16, 0, 0)

// ---------- fp32 -> bf16 bulk convert (8 elems/thread)
__global__ __launch_bounds__(256) void cvt_bf16(const float* __restrict__ src,
                                                ushort* __restrict__ dst, int n8) {
  int i = blockIdx.x * 256 + threadIdx.x;
  if (i >= n8) return;
  float4 a = *(const float4*)&src[(size_t)i * 8];
  float4 b = *(const float4*)&src[(size_t)i * 8 + 4];
  u32x4 pk = {cvt_pk(a.x, a.y), cvt_pk(a.z, a.w), cvt_pk(b.x, b.y), cvt_pk(b.z, b.w)};
  *(bf16x8*)&dst[(size_t)i * 8] = __builtin_bit_cast(bf16x8, pk);
}

// ---------- tiled 64x64 transpose+convert: fp32 [mat][Edim][Ddim] -> bf16 [mat][Ddim][Edim]
__global__ __launch_bounds__(256) void transpose_w(const float* __restrict__ src,
                                                   ushort* __restrict__ dst,
                                                   int Edim, int Ddim) {
  __shared__ ushort tile[64][130];
  int mat = blockIdx.y;
  int ntd = Ddim >> 6;
  int te = blockIdx.x / ntd, td = blockIdx.x % ntd;
  size_t base = (size_t)mat * Edim * Ddim;
  int t = threadIdx.x;
#pragma unroll
  for (int i = 0; i < 16; i++) {
    int idx = i * 256 + t;
    int r = idx >> 6, c = idx & 63;
    tile[r][c] = f2bf(src[base + (size_t)(te * 64 + r) * Ddim + td * 64 + c]);
  }
  __syncthreads();
#pragma unroll
  for (int i = 0; i < 16; i++) {
    int idx = i * 256 + t;
    int c = idx >> 6, r = idx & 63;
    dst[base + (size_t)(td * 64 + c) * Edim + te * 64 + r] = tile[r][c];
  }
}

// swizzle term for row (row multiple-of-16 bases drop out): ((row + (row>>2)) & 3)
__device__ inline uint swz(uint row) { return (row + (row >> 2)) & 3; }

// ---------- QKV GEMM: xb[8192,768] @ Wt(2304x768 row-major d-major) -> q,k,vt
// grid (64, 18), 256 thr = 4 waves; wave (wr=w>>1, wc=w&1) owns 64x64 of 128x128 tile.
__global__ __launch_bounds__(256) void gemm_qkv(const ushort* __restrict__ X,
                                                const ushort* __restrict__ Wt,
                                                ushort* __restrict__ qkv,
                                                uint* __restrict__ vtg) {
  __shared__ ushort Ash[128 * 32];
  __shared__ ushort Bsh[128 * 32];
  int mb = blockIdx.x, nb = blockIdx.y;
  int t = threadIdx.x, w = t >> 6, lane = t & 63, lo = lane & 15, g = lane >> 4;
  int wr = w >> 1, wc = w & 1;
  const ushort* Ab = X + (size_t)mb * 128 * 768;
  const ushort* Bb = Wt + (size_t)nb * 128 * 768;
  f32x4 acc[4][4];
#pragma unroll
  for (int fi = 0; fi < 4; fi++)
#pragma unroll
    for (int fj = 0; fj < 4; fj++) acc[fi][fj] = (f32x4){0.f, 0.f, 0.f, 0.f};
  uint rsw = swz(lo) << 4;  // read-side swizzle byte offset term (row&15 part only)
  for (int e0 = 0; e0 < 768; e0 += 32) {
#pragma unroll
    for (int j = 0; j < 2; j++) {
      uint ci = w * 128 + j * 64 + lane;
      uint row = ci >> 2, c = ci & 3;
      uint sc = (c ^ swz(row)) << 4;
      GLOAD16((const char*)(Ab + (size_t)row * 768 + e0) + sc, Ash + (w * 128 + j * 64) * 8);
      GLOAD16((const char*)(Bb + (size_t)row * 768 + e0) + sc, Bsh + (w * 128 + j * 64) * 8);
    }
    __syncthreads();
    bf16x8 af[4], bf[4];
#pragma unroll
    for (int fi = 0; fi < 4; fi++) {
      int arow = wr * 64 + fi * 16 + lo;
      af[fi] = *(const bf16x8*)((const char*)Ash + arow * 64 + (((g << 4) ^ rsw)));
      int brow = wc * 64 + fi * 16 + lo;
      bf[fi] = *(const bf16x8*)((const char*)Bsh + brow * 64 + (((g << 4) ^ rsw)));
    }
#pragma unroll
    for (int fi = 0; fi < 4; fi++)
#pragma unroll
      for (int fj = 0; fj < 4; fj++)
        acc[fi][fj] = __builtin_amdgcn_mfma_f32_16x16x32_bf16(af[fi], bf[fj], acc[fi][fj], 0, 0, 0);
    __syncthreads();
  }
  int mat = nb * 2 + wc;  // 0..35
  int ty = mat / 12, h = mat % 12;
  if (ty < 2) {
#pragma unroll
    for (int fi = 0; fi < 4; fi++)
#pragma unroll
      for (int fj = 0; fj < 4; fj++) {
        int d = fj * 16 + lo;
#pragma unroll
        for (int rr = 0; rr < 4; rr++) {
          int m = mb * 128 + wr * 64 + fi * 16 + g * 4 + rr;
          int b = m >> 11, s = m & 2047;
          qkv[(size_t)ty * 6291456 + (size_t)(b * 12 + h) * 131072 + (size_t)s * 64 + d] =
              f2bf(acc[fi][fj][rr]);
        }
      }
  } else {
    // v: transposed pair-packed per head: [32 tiles][64 d][32 kv-pairs] uints
#pragma unroll
    for (int fi = 0; fi < 4; fi++)
#pragma unroll
      for (int fj = 0; fj < 4; fj++) {
        int d = fj * 16 + lo;
#pragma unroll
        for (int rr = 0; rr < 4; rr += 2) {
          int m = mb * 128 + wr * 64 + fi * 16 + g * 4 + rr;
          int b = m >> 11, s = m & 2047;
          uint pk = cvt_pk(acc[fi][fj][rr], acc[fi][fj][rr + 1]);
          vtg[(size_t)(b * 12 + h) * 65536 + (s >> 6) * 2048 + d * 32 + ((s & 63) >> 1)] = pk;
        }
      }
  }
}

// ---------- causal flash attention (unchanged from R5): fixed-max softmax, l via MFMA(ones).
__global__ __launch_bounds__(256, 3) void attn_fwd(const ushort* __restrict__ Qg,
                                                   const ushort* __restrict__ Kg,
                                                   const uint* __restrict__ Vtg,
                                                   ushort* __restrict__ ao) {
  __shared__ ushort Ksh[2][64 * 72];
  __shared__ uint Vsh[2][64 * 36];
  int x = blockIdx.x;
  int head = x % 48;
  int qb = 15 - x / 48;
  int T = 2 * qb + 2;
  int t = threadIdx.x, w = t >> 6, q31 = t & 31, hi = (t & 63) >> 5;
  const ushort* Q = Qg + (size_t)head * 131072;
  const ushort* K = Kg + (size_t)head * 131072;
  const uint* V = Vtg + (size_t)head * 65536;
  int qstart = qb * 128 + 32 * w;
  int qg = qstart + q31;
  bf16x8 qf[4];
#pragma unroll
  for (int s = 0; s < 4; s++)
    qf[s] = *(const bf16x8*)&Q[(size_t)qg * 64 + s * 16 + hi * 8];
  bf16x8 ones;
#pragma unroll
  for (int i = 0; i < 8; i++) ones[i] = (short)0x3F80;
  f32x16 oacc[2], lacc;
#pragma unroll
  for (int r = 0; r < 16; r++) { oacc[0][r] = 0.f; oacc[1][r] = 0.f; lacc[r] = 0.f; }
  int sr = t >> 3, sc = t & 7;
  bf16x8 kreg[2];
  u32x4 vreg[2];
#pragma unroll
  for (int i = 0; i < 2; i++) {
    kreg[i] = *(const bf16x8*)&K[(size_t)(i * 32 + sr) * 64 + sc * 8];
    vreg[i] = *(const u32x4*)&V[(i * 32 + sr) * 32 + sc * 4];
  }
#pragma unroll
  for (int i = 0; i < 2; i++) {
    *(bf16x8*)&Ksh[0][(i * 32 + sr) * 72 + sc * 8] = kreg[i];
    *(u32x4*)&Vsh[0][(i * 32 + sr) * 36 + sc * 4] = vreg[i];
  }
  for (int kb = 0; kb < T; kb++) {
    __syncthreads();
    if (kb + 1 < T) {
      int t1 = (kb + 1) * 64;
#pragma unroll
      for (int i = 0; i < 2; i++) {
        kreg[i] = *(const bf16x8*)&K[(size_t)(t1 + i * 32 + sr) * 64 + sc * 8];
        vreg[i] = *(const u32x4*)&V[(kb + 1) * 2048 + (i * 32 + sr) * 32 + sc * 4];
      }
    }
    int t0 = kb * 64;
    if (t0 <= qstart + 31) {
      const ushort* Kb = Ksh[kb & 1];
      const uint* Vb = Vsh[kb & 1];
      bool act1 = (t0 + 32 <= qstart + 31);
      f32x16 st0, st1;
#pragma unroll
      for (int r = 0; r < 16; r++) { st0[r] = 0.f; st1[r] = 0.f; }
#pragma unroll
      for (int s = 0; s < 4; s++) {
        bf16x8 kf = *(const bf16x8*)&Kb[q31 * 72 + s * 16 + hi * 8];
        st0 = __builtin_amdgcn_mfma_f32_32x32x16_bf16(kf, qf[s], st0, 0, 0, 0);
      }
      if (act1) {
#pragma unroll
        for (int s = 0; s < 4; s++) {
          bf16x8 kf = *(const bf16x8*)&Kb[(32 + q31) * 72 + s * 16 + hi * 8];
          st1 = __builtin_amdgcn_mfma_f32_32x32x16_bf16(kf, qf[s], st1, 0, 0, 0);
        }
      }
      if (t0 + 31 > qstart) {
        int base = t0 - qstart;
#pragma unroll
        for (int r = 0; r < 16; r++) {
          int crow = (r & 3) + 8 * (r >> 2) + 4 * hi;
          if (base + crow > q31) st0[r] = -3e38f;
        }
      }
      if (act1 && (t0 + 63 > qstart)) {
        int base = t0 + 32 - qstart;
#pragma unroll
        for (int r = 0; r < 16; r++) {
          int crow = (r & 3) + 8 * (r >> 2) + 4 * hi;
          if (base + crow > q31) st1[r] = -3e38f;
        }
      }
#pragma unroll
      for (int r = 0; r < 16; r++)
        st0[r] = __builtin_amdgcn_exp2f(st0[r] * SCALE_LOG2E);
      if (act1) {
#pragma unroll
        for (int r = 0; r < 16; r++)
          st1[r] = __builtin_amdgcn_exp2f(st1[r] * SCALE_LOG2E);
      }
      int ns = act1 ? 4 : 2;
      bf16x8 paf[4];
#pragma unroll
      for (int s = 0; s < 4; s++) {
        if (s < ns) {
          const f32x16& sv = (s < 2) ? st0 : st1;
          int rb = (s & 1) * 8;
          uint a = cvt_pk(sv[rb + 0], sv[rb + 1]);
          uint b2 = cvt_pk(sv[rb + 2], sv[rb + 3]);
          uint c = cvt_pk(sv[rb + 4], sv[rb + 5]);
          uint d = cvt_pk(sv[rb + 6], sv[rb + 7]);
          asm volatile("v_permlane32_swap_b32 %0, %1" : "+v"(a), "+v"(c));
          asm volatile("v_permlane32_swap_b32 %0, %1" : "+v"(b2), "+v"(d));
          u32x4 u4 = {a, b2, c, d};
          paf[s] = __builtin_bit_cast(bf16x8, u4);
        }
      }
#pragma unroll
      for (int s = 0; s < 4; s++) {
        if (s < ns) {
          lacc = __builtin_amdgcn_mfma_f32_32x32x16_bf16(paf[s], ones, lacc, 0, 0, 0);
#pragma unroll
          for (int dt = 0; dt < 2; dt++) {
            bf16x8 vf = *(const bf16x8*)&Vb[(dt * 32 + q31) * 36 + s * 8 + hi * 4];
            oacc[dt] = __builtin_amdgcn_mfma_f32_32x32x16_bf16(paf[s], vf, oacc[dt], 0, 0, 0);
          }
        }
      }
    }
    if (kb + 1 < T) {
      int b2 = (kb + 1) & 1;
#pragma unroll
      for (int i = 0; i < 2; i++) {
        *(bf16x8*)&Ksh[b2][(i * 32 + sr) * 72 + sc * 8] = kreg[i];
        *(u32x4*)&Vsh[b2][(i * 32 + sr) * 36 + sc * 4] = vreg[i];
      }
    }
  }
  int hh = head % 12, bb = head / 12;
#pragma unroll
  for (int dt = 0; dt < 2; dt++)
#pragma unroll
    for (int r = 0; r < 16; r++) {
      int qr = qstart + (r & 3) + 8 * (r >> 2) + 4 * hi;
      ao[(size_t)(bb * 2048 + qr) * 768 + hh * 64 + dt * 32 + q31] =
          f2bf(oacc[dt][r] / lacc[r]);
    }
}

// ---------- output projection: ao[8192,768] @ Wpt + bp -> out fp32.
// grid (64, 12), 128 thr = 2 waves; wave w owns rows w*64 of a 128x64 tile.
__global__ __launch_bounds__(128) void gemm_out(const ushort* __restrict__ A,
                                                const ushort* __restrict__ Bt,
                                                const float* __restrict__ bias,
                                                float* __restrict__ out) {
  __shared__ ushort Ash[128 * 32];
  __shared__ ushort Bsh[64 * 32];
  int mb = blockIdx.x, nb = blockIdx.y;
  int t = threadIdx.x, w = t >> 6, lane = t & 63, lo = lane & 15, g = lane >> 4;
  const ushort* Ab = A + (size_t)mb * 128 * 768;
  const ushort* Bb = Bt + (size_t)nb * 64 * 768;
  f32x4 acc[4][4];
#pragma unroll
  for (int fi = 0; fi < 4; fi++)
#pragma unroll
    for (int fj = 0; fj < 4; fj++) acc[fi][fj] = (f32x4){0.f, 0.f, 0.f, 0.f};
  uint rsw = swz(lo) << 4;
  for (int e0 = 0; e0 < 768; e0 += 32) {
#pragma unroll
    for (int j = 0; j < 4; j++) {
      uint ci = w * 256 + j * 64 + lane;
      uint row = ci >> 2, c = ci & 3;
      uint sc = (c ^ swz(row)) << 4;
      GLOAD16((const char*)(Ab + (size_t)row * 768 + e0) + sc, Ash + (w * 256 + j * 64) * 8);
    }
#pragma unroll
    for (int j = 0; j < 2; j++) {
      uint ci = w * 128 + j * 64 + lane;
      uint row = ci >> 2, c = ci & 3;
      uint sc = (c ^ swz(row)) << 4;
      GLOAD16((const char*)(Bb + (size_t)row * 768 + e0) + sc, Bsh + (w * 128 + j * 64) * 8);
    }
    __syncthreads();
    bf16x8 af[4], bf[4];
#pragma unroll
    for (int fi = 0; fi < 4; fi++) {
      int arow = w * 64 + fi * 16 + lo;
      af[fi] = *(const bf16x8*)((const char*)Ash + arow * 64 + ((g << 4) ^ rsw));
      int brow = fi * 16 + lo;
      bf[fi] = *(const bf16x8*)((const char*)Bsh + brow * 64 + ((g << 4) ^ rsw));
    }
#pragma unroll
    for (int fi = 0; fi < 4; fi++)
#pragma unroll
      for (int fj = 0; fj < 4; fj++)
        acc[fi][fj] = __builtin_amdgcn_mfma_f32_16x16x32_bf16(af[fi], bf[fj], acc[fi][fj], 0, 0, 0);
    __syncthreads();
  }
#pragma unroll
  for (int fj = 0; fj < 4; fj++) {
    int col = nb * 64 + fj * 16 + lo;
    float bv = bias[col];
#pragma unroll
    for (int fi = 0; fi < 4; fi++)
#pragma unroll
      for (int rr = 0; rr < 4; rr++) {
        int m = mb * 128 + w * 64 + fi * 16 + g * 4 + rr;
        out[(size_t)m * 768 + col] = acc[fi][fj][rr] + bv;
      }
  }
}

extern "C" void kernel_launch(void* const* d_in, const int* in_sizes, int n_in,
                              void* d_out, int out_size, void* d_ws, size_t ws_size,
                              hipStream_t stream) {
  const float* x  = (const float*)d_in[0];
  const float* Wq = (const float*)d_in[1];
  const float* Wk = (const float*)d_in[2];
  const float* Wv = (const float*)d_in[3];
  const float* Wp = (const float*)d_in[4];
  const float* bp = (const float*)d_in[5];
  float* out = (float*)d_out;
  ushort* ws = (ushort*)d_ws;

  ushort* xb  = ws + OFF_XB;
  ushort* wt  = ws + OFF_WT;
  ushort* wpt = ws + OFF_WPT;
  ushort* qkv = ws + OFF_QKV;                          // q, k
  uint*   vt  = (uint*)(ws + OFF_QKV + 2 * 6291456);   // packed-transposed v
  ushort* ao  = ws + OFF_AO;

  cvt_bf16<<<dim3(3072), 256, 0, stream>>>(x, xb, 786432);
  transpose_w<<<dim3(12, 12), 256, 0, stream>>>(Wq, wt + 0 * 589824, 768, 64);
  transpose_w<<<dim3(12, 12), 256, 0, stream>>>(Wk, wt + 1 * 589824, 768, 64);
  transpose_w<<<dim3(12, 12), 256, 0, stream>>>(Wv, wt + 2 * 589824, 768, 64);
  transpose_w<<<dim3(144, 1), 256, 0, stream>>>(Wp, wpt, 768, 768);

  gemm_qkv<<<dim3(64, 18), 256, 0, stream>>>(xb, wt, qkv, vt);
  attn_fwd<<<dim3(768), 256, 0, stream>>>(qkv, qkv + 6291456, vt, ao);
  gemm_out<<<dim3(64, 12), 128, 0, stream>>>(ao, wpt, bp, out);
}

// Round 8
// 133.710 us; speedup vs baseline: 1.8348x; 1.0800x over previous
//
#include <hip/hip_runtime.h>
#include <hip/hip_bf16.h>

// MultiHeadAttention: B=4 H=12 S=2048 D=64 E=768, causal. fp32 in/out, bf16 MFMA compute.
// R7: both GEMMs get counted-vmcnt double-buffered pipelines (T4): raw s_barrier +
//     vmcnt(N) in one asm block, 2 tiles in flight, stage into just-freed buffer.
//     attn unchanged from R5.

typedef __attribute__((ext_vector_type(8))) short bf16x8;
typedef __attribute__((ext_vector_type(4))) float f32x4;
typedef __attribute__((ext_vector_type(16))) float f32x16;
typedef __attribute__((ext_vector_type(4))) uint u32x4;

// ws offsets in bf16 elements
#define OFF_XB   0            // 8192*768            = 6291456
#define OFF_WT   6291456      // 3 * 12*64*768       = 1769472
#define OFF_WPT  8060928      // 768*768             =  589824
#define OFF_QKV  8650752      // q,k: 2 * 6291456; then vt (uints)
#define OFF_AO   27525120     // 8192*768            = 6291456

#define SCALE_LOG2E 0.1803368801111204f   // (1/8) * log2(e)

__device__ inline ushort f2bf(float f) {
  __hip_bfloat16 h = __float2bfloat16(f);
  return *reinterpret_cast<ushort*>(&h);
}
__device__ inline uint cvt_pk(float lo, float hi) {
  uint r;
  asm("v_cvt_pk_bf16_f32 %0, %1, %2" : "=v"(r) : "v"(lo), "v"(hi));
  return r;
}
#define GLOAD16(g, l)                                                              \
  __builtin_amdgcn_global_load_lds(                                                \
      (const __attribute__((address_space(1))) uint*)(g),                          \
      (__attribute__((address_space(3))) uint*)(l), 16, 0, 0)

// counted-wait + barrier, memory-fenced so the compiler can't add its own drain
#define WAITBAR(n) asm volatile("s_waitcnt vmcnt(" #n ")\ns_barrier" ::: "memory")
#define ENDBAR()   asm volatile("s_waitcnt lgkmcnt(0)\ns_barrier" ::: "memory")

// ---------- fp32 -> bf16 bulk convert (8 elems/thread)
__global__ __launch_bounds__(256) void cvt_bf16(const float* __restrict__ src,
                                                ushort* __restrict__ dst, int n8) {
  int i = blockIdx.x * 256 + threadIdx.x;
  if (i >= n8) return;
  float4 a = *(const float4*)&src[(size_t)i * 8];
  float4 b = *(const float4*)&src[(size_t)i * 8 + 4];
  u32x4 pk = {cvt_pk(a.x, a.y), cvt_pk(a.z, a.w), cvt_pk(b.x, b.y), cvt_pk(b.z, b.w)};
  *(bf16x8*)&dst[(size_t)i * 8] = __builtin_bit_cast(bf16x8, pk);
}

// ---------- tiled 64x64 transpose+convert: fp32 [mat][Edim][Ddim] -> bf16 [mat][Ddim][Edim]
__global__ __launch_bounds__(256) void transpose_w(const float* __restrict__ src,
                                                   ushort* __restrict__ dst,
                                                   int Edim, int Ddim) {
  __shared__ ushort tile[64][130];
  int mat = blockIdx.y;
  int ntd = Ddim >> 6;
  int te = blockIdx.x / ntd, td = blockIdx.x % ntd;
  size_t base = (size_t)mat * Edim * Ddim;
  int t = threadIdx.x;
#pragma unroll
  for (int i = 0; i < 16; i++) {
    int idx = i * 256 + t;
    int r = idx >> 6, c = idx & 63;
    tile[r][c] = f2bf(src[base + (size_t)(te * 64 + r) * Ddim + td * 64 + c]);
  }
  __syncthreads();
#pragma unroll
  for (int i = 0; i < 16; i++) {
    int idx = i * 256 + t;
    int c = idx >> 6, r = idx & 63;
    dst[base + (size_t)(td * 64 + c) * Edim + te * 64 + r] = tile[r][c];
  }
}

// swizzle term for row (row multiple-of-16 bases drop out): ((row + (row>>2)) & 3)
__device__ inline uint swz(uint row) { return (row + (row >> 2)) & 3; }

// ---------- QKV GEMM: xb[8192,768] @ Wt(2304x768) -> q,k,vt
// grid (64, 18), 256 thr = 4 waves; wave (wr=w>>1, wc=w&1) owns 64x64 of 128x128 tile.
// Counted-vmcnt double-buffered K-pipeline: 2 tiles in flight, 4 vmem/tile/thread.
__global__ __launch_bounds__(256) void gemm_qkv(const ushort* __restrict__ X,
                                                const ushort* __restrict__ Wt,
                                                ushort* __restrict__ qkv,
                                                uint* __restrict__ vtg) {
  __shared__ ushort Ash[2][128 * 32];
  __shared__ ushort Bsh[2][128 * 32];
  int mb = blockIdx.x, nb = blockIdx.y;
  int t = threadIdx.x, w = t >> 6, lane = t & 63, lo = lane & 15, g = lane >> 4;
  int wr = w >> 1, wc = w & 1;
  const ushort* Ab = X + (size_t)mb * 128 * 768;
  const ushort* Bb = Wt + (size_t)nb * 128 * 768;
  f32x4 acc[4][4];
#pragma unroll
  for (int fi = 0; fi < 4; fi++)
#pragma unroll
    for (int fj = 0; fj < 4; fj++) acc[fi][fj] = (f32x4){0.f, 0.f, 0.f, 0.f};
  // staging source mapping (per lane)
  uint ci0 = w * 128 + lane, ci1 = w * 128 + 64 + lane;
  uint row0 = ci0 >> 2, sc0 = ((ci0 & 3) ^ swz(ci0 >> 2)) << 4;
  uint row1 = ci1 >> 2, sc1 = ((ci1 & 3) ^ swz(ci1 >> 2)) << 4;

#define QKV_STAGE(tile, bsel)                                                        \
  {                                                                                  \
    int e0 = (tile) * 32;                                                            \
    GLOAD16((const char*)(Ab + (size_t)row0 * 768 + e0) + sc0, &Ash[bsel][(w * 128) * 8]);      \
    GLOAD16((const char*)(Bb + (size_t)row0 * 768 + e0) + sc0, &Bsh[bsel][(w * 128) * 8]);      \
    GLOAD16((const char*)(Ab + (size_t)row1 * 768 + e0) + sc1, &Ash[bsel][(w * 128 + 64) * 8]); \
    GLOAD16((const char*)(Bb + (size_t)row1 * 768 + e0) + sc1, &Bsh[bsel][(w * 128 + 64) * 8]); \
  }

  QKV_STAGE(0, 0);
  QKV_STAGE(1, 1);
  uint rsw = swz(lo) << 4;
  for (int it = 0; it < 24; ++it) {
    if (it < 23) { WAITBAR(4); } else { WAITBAR(0); }
    const ushort* Acur = Ash[it & 1];
    const ushort* Bcur = Bsh[it & 1];
    bf16x8 af[4], bf[4];
#pragma unroll
    for (int fi = 0; fi < 4; fi++) {
      int arow = wr * 64 + fi * 16 + lo;
      af[fi] = *(const bf16x8*)((const char*)Acur + arow * 64 + ((g << 4) ^ rsw));
      int brow = wc * 64 + fi * 16 + lo;
      bf[fi] = *(const bf16x8*)((const char*)Bcur + brow * 64 + ((g << 4) ^ rsw));
    }
#pragma unroll
    for (int fi = 0; fi < 4; fi++)
#pragma unroll
      for (int fj = 0; fj < 4; fj++)
        acc[fi][fj] = __builtin_amdgcn_mfma_f32_16x16x32_bf16(af[fi], bf[fj], acc[fi][fj], 0, 0, 0);
    if (it < 22) {
      ENDBAR();
      QKV_STAGE(it + 2, it & 1);
    }
  }
#undef QKV_STAGE
  int mat = nb * 2 + wc;  // 0..35
  int ty = mat / 12, h = mat % 12;
  if (ty < 2) {
#pragma unroll
    for (int fi = 0; fi < 4; fi++)
#pragma unroll
      for (int fj = 0; fj < 4; fj++) {
        int d = fj * 16 + lo;
#pragma unroll
        for (int rr = 0; rr < 4; rr++) {
          int m = mb * 128 + wr * 64 + fi * 16 + g * 4 + rr;
          int b = m >> 11, s = m & 2047;
          qkv[(size_t)ty * 6291456 + (size_t)(b * 12 + h) * 131072 + (size_t)s * 64 + d] =
              f2bf(acc[fi][fj][rr]);
        }
      }
  } else {
    // v: transposed pair-packed per head: [32 tiles][64 d][32 kv-pairs] uints
#pragma unroll
    for (int fi = 0; fi < 4; fi++)
#pragma unroll
      for (int fj = 0; fj < 4; fj++) {
        int d = fj * 16 + lo;
#pragma unroll
        for (int rr = 0; rr < 4; rr += 2) {
          int m = mb * 128 + wr * 64 + fi * 16 + g * 4 + rr;
          int b = m >> 11, s = m & 2047;
          uint pk = cvt_pk(acc[fi][fj][rr], acc[fi][fj][rr + 1]);
          vtg[(size_t)(b * 12 + h) * 65536 + (s >> 6) * 2048 + d * 32 + ((s & 63) >> 1)] = pk;
        }
      }
  }
}

// ---------- causal flash attention (unchanged): fixed-max softmax, l via MFMA(ones).
__global__ __launch_bounds__(256, 3) void attn_fwd(const ushort* __restrict__ Qg,
                                                   const ushort* __restrict__ Kg,
                                                   const uint* __restrict__ Vtg,
                                                   ushort* __restrict__ ao) {
  __shared__ ushort Ksh[2][64 * 72];
  __shared__ uint Vsh[2][64 * 36];
  int x = blockIdx.x;
  int head = x % 48;
  int qb = 15 - x / 48;
  int T = 2 * qb + 2;
  int t = threadIdx.x, w = t >> 6, q31 = t & 31, hi = (t & 63) >> 5;
  const ushort* Q = Qg + (size_t)head * 131072;
  const ushort* K = Kg + (size_t)head * 131072;
  const uint* V = Vtg + (size_t)head * 65536;
  int qstart = qb * 128 + 32 * w;
  int qg = qstart + q31;
  bf16x8 qf[4];
#pragma unroll
  for (int s = 0; s < 4; s++)
    qf[s] = *(const bf16x8*)&Q[(size_t)qg * 64 + s * 16 + hi * 8];
  bf16x8 ones;
#pragma unroll
  for (int i = 0; i < 8; i++) ones[i] = (short)0x3F80;
  f32x16 oacc[2], lacc;
#pragma unroll
  for (int r = 0; r < 16; r++) { oacc[0][r] = 0.f; oacc[1][r] = 0.f; lacc[r] = 0.f; }
  int sr = t >> 3, sc = t & 7;
  bf16x8 kreg[2];
  u32x4 vreg[2];
#pragma unroll
  for (int i = 0; i < 2; i++) {
    kreg[i] = *(const bf16x8*)&K[(size_t)(i * 32 + sr) * 64 + sc * 8];
    vreg[i] = *(const u32x4*)&V[(i * 32 + sr) * 32 + sc * 4];
  }
#pragma unroll
  for (int i = 0; i < 2; i++) {
    *(bf16x8*)&Ksh[0][(i * 32 + sr) * 72 + sc * 8] = kreg[i];
    *(u32x4*)&Vsh[0][(i * 32 + sr) * 36 + sc * 4] = vreg[i];
  }
  for (int kb = 0; kb < T; kb++) {
    __syncthreads();
    if (kb + 1 < T) {
      int t1 = (kb + 1) * 64;
#pragma unroll
      for (int i = 0; i < 2; i++) {
        kreg[i] = *(const bf16x8*)&K[(size_t)(t1 + i * 32 + sr) * 64 + sc * 8];
        vreg[i] = *(const u32x4*)&V[(kb + 1) * 2048 + (i * 32 + sr) * 32 + sc * 4];
      }
    }
    int t0 = kb * 64;
    if (t0 <= qstart + 31) {
      const ushort* Kb = Ksh[kb & 1];
      const uint* Vb = Vsh[kb & 1];
      bool act1 = (t0 + 32 <= qstart + 31);
      f32x16 st0, st1;
#pragma unroll
      for (int r = 0; r < 16; r++) { st0[r] = 0.f; st1[r] = 0.f; }
#pragma unroll
      for (int s = 0; s < 4; s++) {
        bf16x8 kf = *(const bf16x8*)&Kb[q31 * 72 + s * 16 + hi * 8];
        st0 = __builtin_amdgcn_mfma_f32_32x32x16_bf16(kf, qf[s], st0, 0, 0, 0);
      }
      if (act1) {
#pragma unroll
        for (int s = 0; s < 4; s++) {
          bf16x8 kf = *(const bf16x8*)&Kb[(32 + q31) * 72 + s * 16 + hi * 8];
          st1 = __builtin_amdgcn_mfma_f32_32x32x16_bf16(kf, qf[s], st1, 0, 0, 0);
        }
      }
      if (t0 + 31 > qstart) {
        int base = t0 - qstart;
#pragma unroll
        for (int r = 0; r < 16; r++) {
          int crow = (r & 3) + 8 * (r >> 2) + 4 * hi;
          if (base + crow > q31) st0[r] = -3e38f;
        }
      }
      if (act1 && (t0 + 63 > qstart)) {
        int base = t0 + 32 - qstart;
#pragma unroll
        for (int r = 0; r < 16; r++) {
          int crow = (r & 3) + 8 * (r >> 2) + 4 * hi;
          if (base + crow > q31) st1[r] = -3e38f;
        }
      }
#pragma unroll
      for (int r = 0; r < 16; r++)
        st0[r] = __builtin_amdgcn_exp2f(st0[r] * SCALE_LOG2E);
      if (act1) {
#pragma unroll
        for (int r = 0; r < 16; r++)
          st1[r] = __builtin_amdgcn_exp2f(st1[r] * SCALE_LOG2E);
      }
      int ns = act1 ? 4 : 2;
      bf16x8 paf[4];
#pragma unroll
      for (int s = 0; s < 4; s++) {
        if (s < ns) {
          const f32x16& sv = (s < 2) ? st0 : st1;
          int rb = (s & 1) * 8;
          uint a = cvt_pk(sv[rb + 0], sv[rb + 1]);
          uint b2 = cvt_pk(sv[rb + 2], sv[rb + 3]);
          uint c = cvt_pk(sv[rb + 4], sv[rb + 5]);
          uint d = cvt_pk(sv[rb + 6], sv[rb + 7]);
          asm volatile("v_permlane32_swap_b32 %0, %1" : "+v"(a), "+v"(c));
          asm volatile("v_permlane32_swap_b32 %0, %1" : "+v"(b2), "+v"(d));
          u32x4 u4 = {a, b2, c, d};
          paf[s] = __builtin_bit_cast(bf16x8, u4);
        }
      }
#pragma unroll
      for (int s = 0; s < 4; s++) {
        if (s < ns) {
          lacc = __builtin_amdgcn_mfma_f32_32x32x16_bf16(paf[s], ones, lacc, 0, 0, 0);
#pragma unroll
          for (int dt = 0; dt < 2; dt++) {
            bf16x8 vf = *(const bf16x8*)&Vb[(dt * 32 + q31) * 36 + s * 8 + hi * 4];
            oacc[dt] = __builtin_amdgcn_mfma_f32_32x32x16_bf16(paf[s], vf, oacc[dt], 0, 0, 0);
          }
        }
      }
    }
    if (kb + 1 < T) {
      int b2 = (kb + 1) & 1;
#pragma unroll
      for (int i = 0; i < 2; i++) {
        *(bf16x8*)&Ksh[b2][(i * 32 + sr) * 72 + sc * 8] = kreg[i];
        *(u32x4*)&Vsh[b2][(i * 32 + sr) * 36 + sc * 4] = vreg[i];
      }
    }
  }
  int hh = head % 12, bb = head / 12;
#pragma unroll
  for (int dt = 0; dt < 2; dt++)
#pragma unroll
    for (int r = 0; r < 16; r++) {
      int qr = qstart + (r & 3) + 8 * (r >> 2) + 4 * hi;
      ao[(size_t)(bb * 2048 + qr) * 768 + hh * 64 + dt * 32 + q31] =
          f2bf(oacc[dt][r] / lacc[r]);
    }
}

// ---------- output projection: ao[8192,768] @ Wpt + bp -> out fp32.
// grid (64, 12), 128 thr = 2 waves; wave w owns rows w*64 of 128x64 tile.
// Counted-vmcnt double-buffered pipeline, 6 vmem/tile/thread.
__global__ __launch_bounds__(128) void gemm_out(const ushort* __restrict__ A,
                                                const ushort* __restrict__ Bt,
                                                const float* __restrict__ bias,
                                                float* __restrict__ out) {
  __shared__ ushort Ash[2][128 * 32];
  __shared__ ushort Bsh[2][64 * 32];
  int mb = blockIdx.x, nb = blockIdx.y;
  int t = threadIdx.x, w = t >> 6, lane = t & 63, lo = lane & 15, g = lane >> 4;
  const ushort* Ab = A + (size_t)mb * 128 * 768;
  const ushort* Bb = Bt + (size_t)nb * 64 * 768;
  f32x4 acc[4][4];
#pragma unroll
  for (int fi = 0; fi < 4; fi++)
#pragma unroll
    for (int fj = 0; fj < 4; fj++) acc[fi][fj] = (f32x4){0.f, 0.f, 0.f, 0.f};
  uint aci[4], asc[4], bci[2], bsc[2];
#pragma unroll
  for (int j = 0; j < 4; j++) {
    uint ci = w * 256 + j * 64 + lane;
    aci[j] = ci;
    asc[j] = ((ci & 3) ^ swz(ci >> 2)) << 4;
  }
#pragma unroll
  for (int j = 0; j < 2; j++) {
    uint ci = w * 128 + j * 64 + lane;
    bci[j] = ci;
    bsc[j] = ((ci & 3) ^ swz(ci >> 2)) << 4;
  }

#define OUT_STAGE(tile, bsel)                                                          \
  {                                                                                    \
    int e0 = (tile) * 32;                                                              \
    _Pragma("unroll")                                                                  \
    for (int j = 0; j < 4; j++)                                                        \
      GLOAD16((const char*)(Ab + (size_t)(aci[j] >> 2) * 768 + e0) + asc[j],           \
              &Ash[bsel][(w * 256 + j * 64) * 8]);                                     \
    _Pragma("unroll")                                                                  \
    for (int j = 0; j < 2; j++)                                                        \
      GLOAD16((const char*)(Bb + (size_t)(bci[j] >> 2) * 768 + e0) + bsc[j],           \
              &Bsh[bsel][(w * 128 + j * 64) * 8]);                                     \
  }

  OUT_STAGE(0, 0);
  OUT_STAGE(1, 1);
  uint rsw = swz(lo) << 4;
  for (int it = 0; it < 24; ++it) {
    if (it < 23) { WAITBAR(6); } else { WAITBAR(0); }
    const ushort* Acur = Ash[it & 1];
    const ushort* Bcur = Bsh[it & 1];
    bf16x8 af[4], bf[4];
#pragma unroll
    for (int fi = 0; fi < 4; fi++) {
      int arow = w * 64 + fi * 16 + lo;
      af[fi] = *(const bf16x8*)((const char*)Acur + arow * 64 + ((g << 4) ^ rsw));
      int brow = fi * 16 + lo;
      bf[fi] = *(const bf16x8*)((const char*)Bcur + brow * 64 + ((g << 4) ^ rsw));
    }
#pragma unroll
    for (int fi = 0; fi < 4; fi++)
#pragma unroll
      for (int fj = 0; fj < 4; fj++)
        acc[fi][fj] = __builtin_amdgcn_mfma_f32_16x16x32_bf16(af[fi], bf[fj], acc[fi][fj], 0, 0, 0);
    if (it < 22) {
      ENDBAR();
      OUT_STAGE(it + 2, it & 1);
    }
  }
#undef OUT_STAGE
#pragma unroll
  for (int fj = 0; fj < 4; fj++) {
    int col = nb * 64 + fj * 16 + lo;
    float bv = bias[col];
#pragma unroll
    for (int fi = 0; fi < 4; fi++)
#pragma unroll
      for (int rr = 0; rr < 4; rr++) {
        int m = mb * 128 + w * 64 + fi * 16 + g * 4 + rr;
        out[(size_t)m * 768 + col] = acc[fi][fj][rr] + bv;
      }
  }
}

extern "C" void kernel_launch(void* const* d_in, const int* in_sizes, int n_in,
                              void* d_out, int out_size, void* d_ws, size_t ws_size,
                              hipStream_t stream) {
  const float* x  = (const float*)d_in[0];
  const float* Wq = (const float*)d_in[1];
  const float* Wk = (const float*)d_in[2];
  const float* Wv = (const float*)d_in[3];
  const float* Wp = (const float*)d_in[4];
  const float* bp = (const float*)d_in[5];
  float* out = (float*)d_out;
  ushort* ws = (ushort*)d_ws;

  ushort* xb  = ws + OFF_XB;
  ushort* wt  = ws + OFF_WT;
  ushort* wpt = ws + OFF_WPT;
  ushort* qkv = ws + OFF_QKV;                          // q, k
  uint*   vt  = (uint*)(ws + OFF_QKV + 2 * 6291456);   // packed-transposed v
  ushort* ao  = ws + OFF_AO;

  cvt_bf16<<<dim3(3072), 256, 0, stream>>>(x, xb, 786432);
  transpose_w<<<dim3(12, 12), 256, 0, stream>>>(Wq, wt + 0 * 589824, 768, 64);
  transpose_w<<<dim3(12, 12), 256, 0, stream>>>(Wk, wt + 1 * 589824, 768, 64);
  transpose_w<<<dim3(12, 12), 256, 0, stream>>>(Wv, wt + 2 * 589824, 768, 64);
  transpose_w<<<dim3(144, 1), 256, 0, stream>>>(Wp, wpt, 768, 768);

  gemm_qkv<<<dim3(64, 18), 256, 0, stream>>>(xb, wt, qkv, vt);
  attn_fwd<<<dim3(768), 256, 0, stream>>>(qkv, qkv + 6291456, vt, ao);
  gemm_out<<<dim3(64, 12), 128, 0, stream>>>(ao, wpt, bp, out);
}

// Round 9
// 129.386 us; speedup vs baseline: 1.8961x; 1.0334x over previous
//
#include <hip/hip_runtime.h>
#include <hip/hip_bf16.h>

// MultiHeadAttention: B=4 H=12 S=2048 D=64 E=768, causal. fp32 in/out, bf16 MFMA compute.
// R8: GEMMs restructured: 128x128 block / 2 waves / 64x128 per wave (acc 4x8 f32x4),
//     counted-vmcnt dbuf kept, 5 blocks/CU. Transposes merged. attn unchanged.

typedef __attribute__((ext_vector_type(8))) short bf16x8;
typedef __attribute__((ext_vector_type(4))) float f32x4;
typedef __attribute__((ext_vector_type(16))) float f32x16;
typedef __attribute__((ext_vector_type(4))) uint u32x4;

// ws offsets in bf16 elements
#define OFF_XB   0            // 8192*768            = 6291456
#define OFF_WT   6291456      // 3 * 12*64*768       = 1769472
#define OFF_WPT  8060928      // 768*768             =  589824
#define OFF_QKV  8650752      // q,k: 2 * 6291456; then vt (uints)
#define OFF_AO   27525120     // 8192*768            = 6291456

#define SCALE_LOG2E 0.1803368801111204f   // (1/8) * log2(e)

__device__ inline ushort f2bf(float f) {
  __hip_bfloat16 h = __float2bfloat16(f);
  return *reinterpret_cast<ushort*>(&h);
}
__device__ inline uint cvt_pk(float lo, float hi) {
  uint r;
  asm("v_cvt_pk_bf16_f32 %0, %1, %2" : "=v"(r) : "v"(lo), "v"(hi));
  return r;
}
#define GLOAD16(g, l)                                                              \
  __builtin_amdgcn_global_load_lds(                                                \
      (const __attribute__((address_space(1))) uint*)(g),                          \
      (__attribute__((address_space(3))) uint*)(l), 16, 0, 0)

// counted-wait + barrier, memory-fenced so the compiler can't add its own drain
#define WAITBAR(n) asm volatile("s_waitcnt vmcnt(" #n ")\ns_barrier" ::: "memory")
#define ENDBAR()   asm volatile("s_waitcnt lgkmcnt(0)\ns_barrier" ::: "memory")

// ---------- fp32 -> bf16 bulk convert (8 elems/thread)
__global__ __launch_bounds__(256) void cvt_bf16(const float* __restrict__ src,
                                                ushort* __restrict__ dst, int n8) {
  int i = blockIdx.x * 256 + threadIdx.x;
  if (i >= n8) return;
  float4 a = *(const float4*)&src[(size_t)i * 8];
  float4 b = *(const float4*)&src[(size_t)i * 8 + 4];
  u32x4 pk = {cvt_pk(a.x, a.y), cvt_pk(a.z, a.w), cvt_pk(b.x, b.y), cvt_pk(b.z, b.w)};
  *(bf16x8*)&dst[(size_t)i * 8] = __builtin_bit_cast(bf16x8, pk);
}

// ---------- tiled 64x64 transpose+convert for the three QKV weights (z = mat 0..35)
__global__ __launch_bounds__(256) void transpose_wqkv(const float* __restrict__ Wq,
                                                      const float* __restrict__ Wk,
                                                      const float* __restrict__ Wv,
                                                      ushort* __restrict__ dst) {
  __shared__ ushort tile[64][130];
  int mat = blockIdx.y;       // 0..35
  int te = blockIdx.x;        // 0..11 (E tiles); Ddim = 64 -> single d tile
  const float* src = (mat < 12) ? Wq : (mat < 24) ? Wk : Wv;
  int m12 = mat % 12;
  size_t base = (size_t)m12 * 768 * 64;
  int t = threadIdx.x;
#pragma unroll
  for (int i = 0; i < 16; i++) {
    int idx = i * 256 + t;
    int r = idx >> 6, c = idx & 63;
    tile[r][c] = f2bf(src[base + (size_t)(te * 64 + r) * 64 + c]);
  }
  __syncthreads();
  size_t obase = (size_t)mat * 49152;  // 64*768
#pragma unroll
  for (int i = 0; i < 16; i++) {
    int idx = i * 256 + t;
    int c = idx >> 6, r = idx & 63;
    dst[obase + (size_t)c * 768 + te * 64 + r] = tile[r][c];
  }
}

// ---------- tiled 64x64 transpose+convert: fp32 [Edim][Ddim] -> bf16 [Ddim][Edim]
__global__ __launch_bounds__(256) void transpose_w(const float* __restrict__ src,
                                                   ushort* __restrict__ dst,
                                                   int Edim, int Ddim) {
  __shared__ ushort tile[64][130];
  int ntd = Ddim >> 6;
  int te = blockIdx.x / ntd, td = blockIdx.x % ntd;
  int t = threadIdx.x;
#pragma unroll
  for (int i = 0; i < 16; i++) {
    int idx = i * 256 + t;
    int r = idx >> 6, c = idx & 63;
    tile[r][c] = f2bf(src[(size_t)(te * 64 + r) * Ddim + td * 64 + c]);
  }
  __syncthreads();
#pragma unroll
  for (int i = 0; i < 16; i++) {
    int idx = i * 256 + t;
    int c = idx >> 6, r = idx & 63;
    dst[(size_t)(td * 64 + c) * Edim + te * 64 + r] = tile[r][c];
  }
}

// swizzle term for row (row multiple-of-16 bases drop out): ((row + (row>>2)) & 3)
__device__ inline uint swz(uint row) { return (row + (row >> 2)) & 3; }

// ---------- QKV GEMM: xb[8192,768] @ Wt(2304x768) -> q,k,vt
// grid (64, 18), 128 thr = 2 waves; wave w owns rows w*64, all 128 cols.
// acc[4][8]; counted-vmcnt dbuf, 8 gloads/thread/tile.
__global__ __launch_bounds__(128, 2) void gemm_qkv(const ushort* __restrict__ X,
                                                   const ushort* __restrict__ Wt,
                                                   ushort* __restrict__ qkv,
                                                   uint* __restrict__ vtg) {
  __shared__ ushort Ash[2][128 * 32];
  __shared__ ushort Bsh[2][128 * 32];
  int mb = blockIdx.x, nb = blockIdx.y;
  int t = threadIdx.x, w = t >> 6, lane = t & 63, lo = lane & 15, g = lane >> 4;
  const ushort* Ab = X + (size_t)mb * 128 * 768;
  const ushort* Bb = Wt + (size_t)nb * 128 * 768;
  f32x4 acc[4][8];
#pragma unroll
  for (int fi = 0; fi < 4; fi++)
#pragma unroll
    for (int fj = 0; fj < 8; fj++) acc[fi][fj] = (f32x4){0.f, 0.f, 0.f, 0.f};
  // staging source mapping: 4 chunks each for A and B per tile
  uint srow[4], ssc[4];
#pragma unroll
  for (int j = 0; j < 4; j++) {
    uint ci = j * 128 + t;
    srow[j] = ci >> 2;
    ssc[j] = ((ci & 3) ^ swz(ci >> 2)) << 4;
  }

#define QKV_STAGE(tile, bsel)                                                         \
  {                                                                                   \
    int e0 = (tile) * 32;                                                             \
    _Pragma("unroll")                                                                 \
    for (int j = 0; j < 4; j++) {                                                     \
      GLOAD16((const char*)(Ab + (size_t)srow[j] * 768 + e0) + ssc[j],                \
              &Ash[bsel][(j * 128 + w * 64) * 8]);                                    \
      GLOAD16((const char*)(Bb + (size_t)srow[j] * 768 + e0) + ssc[j],                \
              &Bsh[bsel][(j * 128 + w * 64) * 8]);                                    \
    }                                                                                 \
  }

  QKV_STAGE(0, 0);
  QKV_STAGE(1, 1);
  uint rsw = swz(lo) << 4;
  for (int it = 0; it < 24; ++it) {
    if (it < 23) { WAITBAR(8); } else { WAITBAR(0); }
    const ushort* Acur = Ash[it & 1];
    const ushort* Bcur = Bsh[it & 1];
    bf16x8 af[4], bf[8];
#pragma unroll
    for (int fi = 0; fi < 4; fi++) {
      int arow = w * 64 + fi * 16 + lo;
      af[fi] = *(const bf16x8*)((const char*)Acur + arow * 64 + ((g << 4) ^ rsw));
    }
#pragma unroll
    for (int fj = 0; fj < 8; fj++) {
      int brow = fj * 16 + lo;
      bf[fj] = *(const bf16x8*)((const char*)Bcur + brow * 64 + ((g << 4) ^ rsw));
    }
#pragma unroll
    for (int fi = 0; fi < 4; fi++)
#pragma unroll
      for (int fj = 0; fj < 8; fj++)
        acc[fi][fj] = __builtin_amdgcn_mfma_f32_16x16x32_bf16(af[fi], bf[fj], acc[fi][fj], 0, 0, 0);
    if (it < 22) {
      ENDBAR();
      QKV_STAGE(it + 2, it & 1);
    }
  }
#undef QKV_STAGE
#pragma unroll
  for (int fj = 0; fj < 8; fj++) {
    int mat = nb * 2 + (fj >> 2);  // 0..35
    int ty = mat / 12, h = mat % 12;
    int d = (fj & 3) * 16 + lo;
    if (ty < 2) {
#pragma unroll
      for (int fi = 0; fi < 4; fi++)
#pragma unroll
        for (int rr = 0; rr < 4; rr++) {
          int m = mb * 128 + w * 64 + fi * 16 + g * 4 + rr;
          int b = m >> 11, s = m & 2047;
          qkv[(size_t)ty * 6291456 + (size_t)(b * 12 + h) * 131072 + (size_t)s * 64 + d] =
              f2bf(acc[fi][fj][rr]);
        }
    } else {
      // v: transposed pair-packed per head: [32 tiles][64 d][32 kv-pairs] uints
#pragma unroll
      for (int fi = 0; fi < 4; fi++)
#pragma unroll
        for (int rr = 0; rr < 4; rr += 2) {
          int m = mb * 128 + w * 64 + fi * 16 + g * 4 + rr;
          int b = m >> 11, s = m & 2047;
          uint pk = cvt_pk(acc[fi][fj][rr], acc[fi][fj][rr + 1]);
          vtg[(size_t)(b * 12 + h) * 65536 + (s >> 6) * 2048 + d * 32 + ((s & 63) >> 1)] = pk;
        }
    }
  }
}

// ---------- causal flash attention (unchanged): fixed-max softmax, l via MFMA(ones).
__global__ __launch_bounds__(256, 3) void attn_fwd(const ushort* __restrict__ Qg,
                                                   const ushort* __restrict__ Kg,
                                                   const uint* __restrict__ Vtg,
                                                   ushort* __restrict__ ao) {
  __shared__ ushort Ksh[2][64 * 72];
  __shared__ uint Vsh[2][64 * 36];
  int x = blockIdx.x;
  int head = x % 48;
  int qb = 15 - x / 48;
  int T = 2 * qb + 2;
  int t = threadIdx.x, w = t >> 6, q31 = t & 31, hi = (t & 63) >> 5;
  const ushort* Q = Qg + (size_t)head * 131072;
  const ushort* K = Kg + (size_t)head * 131072;
  const uint* V = Vtg + (size_t)head * 65536;
  int qstart = qb * 128 + 32 * w;
  int qg = qstart + q31;
  bf16x8 qf[4];
#pragma unroll
  for (int s = 0; s < 4; s++)
    qf[s] = *(const bf16x8*)&Q[(size_t)qg * 64 + s * 16 + hi * 8];
  bf16x8 ones;
#pragma unroll
  for (int i = 0; i < 8; i++) ones[i] = (short)0x3F80;
  f32x16 oacc[2], lacc;
#pragma unroll
  for (int r = 0; r < 16; r++) { oacc[0][r] = 0.f; oacc[1][r] = 0.f; lacc[r] = 0.f; }
  int sr = t >> 3, sc = t & 7;
  bf16x8 kreg[2];
  u32x4 vreg[2];
#pragma unroll
  for (int i = 0; i < 2; i++) {
    kreg[i] = *(const bf16x8*)&K[(size_t)(i * 32 + sr) * 64 + sc * 8];
    vreg[i] = *(const u32x4*)&V[(i * 32 + sr) * 32 + sc * 4];
  }
#pragma unroll
  for (int i = 0; i < 2; i++) {
    *(bf16x8*)&Ksh[0][(i * 32 + sr) * 72 + sc * 8] = kreg[i];
    *(u32x4*)&Vsh[0][(i * 32 + sr) * 36 + sc * 4] = vreg[i];
  }
  for (int kb = 0; kb < T; kb++) {
    __syncthreads();
    if (kb + 1 < T) {
      int t1 = (kb + 1) * 64;
#pragma unroll
      for (int i = 0; i < 2; i++) {
        kreg[i] = *(const bf16x8*)&K[(size_t)(t1 + i * 32 + sr) * 64 + sc * 8];
        vreg[i] = *(const u32x4*)&V[(kb + 1) * 2048 + (i * 32 + sr) * 32 + sc * 4];
      }
    }
    int t0 = kb * 64;
    if (t0 <= qstart + 31) {
      const ushort* Kb = Ksh[kb & 1];
      const uint* Vb = Vsh[kb & 1];
      bool act1 = (t0 + 32 <= qstart + 31);
      f32x16 st0, st1;
#pragma unroll
      for (int r = 0; r < 16; r++) { st0[r] = 0.f; st1[r] = 0.f; }
#pragma unroll
      for (int s = 0; s < 4; s++) {
        bf16x8 kf = *(const bf16x8*)&Kb[q31 * 72 + s * 16 + hi * 8];
        st0 = __builtin_amdgcn_mfma_f32_32x32x16_bf16(kf, qf[s], st0, 0, 0, 0);
      }
      if (act1) {
#pragma unroll
        for (int s = 0; s < 4; s++) {
          bf16x8 kf = *(const bf16x8*)&Kb[(32 + q31) * 72 + s * 16 + hi * 8];
          st1 = __builtin_amdgcn_mfma_f32_32x32x16_bf16(kf, qf[s], st1, 0, 0, 0);
        }
      }
      if (t0 + 31 > qstart) {
        int base = t0 - qstart;
#pragma unroll
        for (int r = 0; r < 16; r++) {
          int crow = (r & 3) + 8 * (r >> 2) + 4 * hi;
          if (base + crow > q31) st0[r] = -3e38f;
        }
      }
      if (act1 && (t0 + 63 > qstart)) {
        int base = t0 + 32 - qstart;
#pragma unroll
        for (int r = 0; r < 16; r++) {
          int crow = (r & 3) + 8 * (r >> 2) + 4 * hi;
          if (base + crow > q31) st1[r] = -3e38f;
        }
      }
#pragma unroll
      for (int r = 0; r < 16; r++)
        st0[r] = __builtin_amdgcn_exp2f(st0[r] * SCALE_LOG2E);
      if (act1) {
#pragma unroll
        for (int r = 0; r < 16; r++)
          st1[r] = __builtin_amdgcn_exp2f(st1[r] * SCALE_LOG2E);
      }
      int ns = act1 ? 4 : 2;
      bf16x8 paf[4];
#pragma unroll
      for (int s = 0; s < 4; s++) {
        if (s < ns) {
          const f32x16& sv = (s < 2) ? st0 : st1;
          int rb = (s & 1) * 8;
          uint a = cvt_pk(sv[rb + 0], sv[rb + 1]);
          uint b2 = cvt_pk(sv[rb + 2], sv[rb + 3]);
          uint c = cvt_pk(sv[rb + 4], sv[rb + 5]);
          uint d = cvt_pk(sv[rb + 6], sv[rb + 7]);
          asm volatile("v_permlane32_swap_b32 %0, %1" : "+v"(a), "+v"(c));
          asm volatile("v_permlane32_swap_b32 %0, %1" : "+v"(b2), "+v"(d));
          u32x4 u4 = {a, b2, c, d};
          paf[s] = __builtin_bit_cast(bf16x8, u4);
        }
      }
#pragma unroll
      for (int s = 0; s < 4; s++) {
        if (s < ns) {
          lacc = __builtin_amdgcn_mfma_f32_32x32x16_bf16(paf[s], ones, lacc, 0, 0, 0);
#pragma unroll
          for (int dt = 0; dt < 2; dt++) {
            bf16x8 vf = *(const bf16x8*)&Vb[(dt * 32 + q31) * 36 + s * 8 + hi * 4];
            oacc[dt] = __builtin_amdgcn_mfma_f32_32x32x16_bf16(paf[s], vf, oacc[dt], 0, 0, 0);
          }
        }
      }
    }
    if (kb + 1 < T) {
      int b2 = (kb + 1) & 1;
#pragma unroll
      for (int i = 0; i < 2; i++) {
        *(bf16x8*)&Ksh[b2][(i * 32 + sr) * 72 + sc * 8] = kreg[i];
        *(u32x4*)&Vsh[b2][(i * 32 + sr) * 36 + sc * 4] = vreg[i];
      }
    }
  }
  int hh = head % 12, bb = head / 12;
#pragma unroll
  for (int dt = 0; dt < 2; dt++)
#pragma unroll
    for (int r = 0; r < 16; r++) {
      int qr = qstart + (r & 3) + 8 * (r >> 2) + 4 * hi;
      ao[(size_t)(bb * 2048 + qr) * 768 + hh * 64 + dt * 32 + q31] =
          f2bf(oacc[dt][r] / lacc[r]);
    }
}

// ---------- output projection: ao[8192,768] @ Wpt + bp -> out fp32.
// grid (64, 6), 128 thr = 2 waves; wave w owns rows w*64, all 128 cols.
__global__ __launch_bounds__(128, 2) void gemm_out(const ushort* __restrict__ A,
                                                   const ushort* __restrict__ Bt,
                                                   const float* __restrict__ bias,
                                                   float* __restrict__ out) {
  __shared__ ushort Ash[2][128 * 32];
  __shared__ ushort Bsh[2][128 * 32];
  int mb = blockIdx.x, nb = blockIdx.y;
  int t = threadIdx.x, w = t >> 6, lane = t & 63, lo = lane & 15, g = lane >> 4;
  const ushort* Ab = A + (size_t)mb * 128 * 768;
  const ushort* Bb = Bt + (size_t)nb * 128 * 768;
  f32x4 acc[4][8];
#pragma unroll
  for (int fi = 0; fi < 4; fi++)
#pragma unroll
    for (int fj = 0; fj < 8; fj++) acc[fi][fj] = (f32x4){0.f, 0.f, 0.f, 0.f};
  uint srow[4], ssc[4];
#pragma unroll
  for (int j = 0; j < 4; j++) {
    uint ci = j * 128 + t;
    srow[j] = ci >> 2;
    ssc[j] = ((ci & 3) ^ swz(ci >> 2)) << 4;
  }

#define OUT_STAGE(tile, bsel)                                                         \
  {                                                                                   \
    int e0 = (tile) * 32;                                                             \
    _Pragma("unroll")                                                                 \
    for (int j = 0; j < 4; j++) {                                                     \
      GLOAD16((const char*)(Ab + (size_t)srow[j] * 768 + e0) + ssc[j],                \
              &Ash[bsel][(j * 128 + w * 64) * 8]);                                    \
      GLOAD16((const char*)(Bb + (size_t)srow[j] * 768 + e0) + ssc[j],                \
              &Bsh[bsel][(j * 128 + w * 64) * 8]);                                    \
    }                                                                                 \
  }

  OUT_STAGE(0, 0);
  OUT_STAGE(1, 1);
  uint rsw = swz(lo) << 4;
  for (int it = 0; it < 24; ++it) {
    if (it < 23) { WAITBAR(8); } else { WAITBAR(0); }
    const ushort* Acur = Ash[it & 1];
    const ushort* Bcur = Bsh[it & 1];
    bf16x8 af[4], bf[8];
#pragma unroll
    for (int fi = 0; fi < 4; fi++) {
      int arow = w * 64 + fi * 16 + lo;
      af[fi] = *(const bf16x8*)((const char*)Acur + arow * 64 + ((g << 4) ^ rsw));
    }
#pragma unroll
    for (int fj = 0; fj < 8; fj++) {
      int brow = fj * 16 + lo;
      bf[fj] = *(const bf16x8*)((const char*)Bcur + brow * 64 + ((g << 4) ^ rsw));
    }
#pragma unroll
    for (int fi = 0; fi < 4; fi++)
#pragma unroll
      for (int fj = 0; fj < 8; fj++)
        acc[fi][fj] = __builtin_amdgcn_mfma_f32_16x16x32_bf16(af[fi], bf[fj], acc[fi][fj], 0, 0, 0);
    if (it < 22) {
      ENDBAR();
      OUT_STAGE(it + 2, it & 1);
    }
  }
#undef OUT_STAGE
#pragma unroll
  for (int fj = 0; fj < 8; fj++) {
    int col = nb * 128 + fj * 16 + lo;
    float bv = bias[col];
#pragma unroll
    for (int fi = 0; fi < 4; fi++)
#pragma unroll
      for (int rr = 0; rr < 4; rr++) {
        int m = mb * 128 + w * 64 + fi * 16 + g * 4 + rr;
        out[(size_t)m * 768 + col] = acc[fi][fj][rr] + bv;
      }
  }
}

extern "C" void kernel_launch(void* const* d_in, const int* in_sizes, int n_in,
                              void* d_out, int out_size, void* d_ws, size_t ws_size,
                              hipStream_t stream) {
  const float* x  = (const float*)d_in[0];
  const float* Wq = (const float*)d_in[1];
  const float* Wk = (const float*)d_in[2];
  const float* Wv = (const float*)d_in[3];
  const float* Wp = (const float*)d_in[4];
  const float* bp = (const float*)d_in[5];
  float* out = (float*)d_out;
  ushort* ws = (ushort*)d_ws;

  ushort* xb  = ws + OFF_XB;
  ushort* wt  = ws + OFF_WT;
  ushort* wpt = ws + OFF_WPT;
  ushort* qkv = ws + OFF_QKV;                          // q, k
  uint*   vt  = (uint*)(ws + OFF_QKV + 2 * 6291456);   // packed-transposed v
  ushort* ao  = ws + OFF_AO;

  cvt_bf16<<<dim3(3072), 256, 0, stream>>>(x, xb, 786432);
  transpose_wqkv<<<dim3(12, 36), 256, 0, stream>>>(Wq, Wk, Wv, wt);
  transpose_w<<<dim3(144), 256, 0, stream>>>(Wp, wpt, 768, 768);

  gemm_qkv<<<dim3(64, 18), 128, 0, stream>>>(xb, wt, qkv, vt);
  attn_fwd<<<dim3(768), 256, 0, stream>>>(qkv, qkv + 6291456, vt, ao);
  gemm_out<<<dim3(64, 6), 128, 0, stream>>>(ao, wpt, bp, out);
}